// Round 1
// baseline (470.329 us; speedup 1.0000x reference)
//
#include <hip/hip_runtime.h>

#define NN 50000
#define NE 800000
#define FD 128
#define KH 384
#define NU 256
#define NG 64
#define MAXDEG 64

typedef __attribute__((__ext_vector_type__(8))) short short8;
typedef __attribute__((__ext_vector_type__(4))) float f32x4;

// ---- ws layout (bytes, all offsets 16B-aligned) ----
#define OFF_CNT   0u           // NN int            (200000)
#define OFF_G     200000u      // 64*256 f32        (65536)   zeroed with cnt
#define OFF_COL   265536u      // NN*MAXDEG int     (12800000)
#define OFF_DINV  13065536u    // NN f32            (200000)
#define OFF_XBF   13265536u    // NN*128 bf16       (12800000)
#define OFF_HBF   26065536u    // NN*128 bf16       (12800000)
#define OFF_H     38865536u    // NN*384 bf16       (38400000)
#define OFF_HH    77265536u    // NN f32            (200000)
#define OFF_DOTS  77465536u    // NN*256 bf16       (25600000)
#define OFF_WT    103065536u   // 3*128*128 bf16    (98304)
#define OFF_SBF   103163840u   // 256*384 bf16      (196608)
#define OFF_SS    103360448u   // 256 f32           (1024)  -> total 103361472

__device__ __forceinline__ float b2f(ushort h){
  union { unsigned u; float f; } c; c.u = ((unsigned)h) << 16; return c.f;
}
__device__ __forceinline__ ushort f2b(float f){
  union { float f; unsigned u; } c; c.f = f;
  unsigned u = c.u;
  return (ushort)((u + 0x7fffu + ((u >> 16) & 1u)) >> 16);
}

__global__ void k_convert(const float* __restrict__ s, ushort* __restrict__ d, int n4){
  int i = blockIdx.x * blockDim.x + threadIdx.x;
  if (i >= n4) return;
  float4 v = reinterpret_cast<const float4*>(s)[i];
  ushort4 o; o.x = f2b(v.x); o.y = f2b(v.y); o.z = f2b(v.z); o.w = f2b(v.w);
  reinterpret_cast<ushort4*>(d)[i] = o;
}

// Wt[n][k] = bf16(W[k][n])  (block = n, thread = k)
__global__ void k_twc(const float* __restrict__ W, ushort* __restrict__ Wt){
  int n = blockIdx.x, k = threadIdx.x;
  Wt[n * FD + k] = f2b(W[k * FD + n]);
}

__global__ void k_count(const int* __restrict__ ei, int* __restrict__ cnt){
  int e = blockIdx.x * blockDim.x + threadIdx.x;
  if (e < NE) atomicAdd(&cnt[ei[NE + e]], 1);
}

__global__ void k_dinv(int* __restrict__ cnt, float* __restrict__ dinv){
  int i = blockIdx.x * blockDim.x + threadIdx.x;
  if (i < NN){ dinv[i] = rsqrtf((float)(cnt[i] + 1)); cnt[i] = 0; }
}

__global__ void k_scatter(const int* __restrict__ ei, int* __restrict__ cnt, int* __restrict__ col){
  int e = blockIdx.x * blockDim.x + threadIdx.x;
  if (e >= NE) return;
  int d = ei[NE + e];
  int pos = atomicAdd(&cnt[d], 1);
  if (pos < MAXDEG) col[(size_t)d * MAXDEG + pos] = ei[e];
}

// C[M][Nt] = A[M][K] * B_T[Nt][K]^T   (all bf16, fp32 accum, bf16 out)
// tile 128x128, BK=64, 4 waves (2x2), mfma_f32_16x16x32_bf16, XOR-swizzled LDS
__global__ __launch_bounds__(256) void k_gemm(
    const ushort* __restrict__ A, int lda,
    const ushort* __restrict__ B, int ldb,
    ushort* __restrict__ C, int ldc, int M, int K){
  __shared__ __align__(16) ushort Al[128 * 64];
  __shared__ __align__(16) ushort Bl[128 * 64];
  const int t = threadIdx.x;
  const int lane = t & 63, w = t >> 6;
  const int wr = w >> 1, wc = w & 1;
  const int ln = lane & 15, hi = lane >> 4;
  const int mBase = blockIdx.x * 128, nBase = blockIdx.y * 128;

  f32x4 zero = {0.f, 0.f, 0.f, 0.f};
  f32x4 acc[4][4];
  #pragma unroll
  for (int i = 0; i < 4; ++i)
    #pragma unroll
    for (int j = 0; j < 4; ++j) acc[i][j] = zero;

  for (int kb = 0; kb < K; kb += 64){
    __syncthreads();
    #pragma unroll
    for (int it = 0; it < 4; ++it){
      int idx = t + it * 256;           // 0..1023
      int row = idx >> 3, seg = idx & 7;
      int off = (row * 128 + seg * 16) ^ ((row & 7) << 4);
      uint4 va = make_uint4(0u, 0u, 0u, 0u);
      int gm = mBase + row;
      if (gm < M) va = *reinterpret_cast<const uint4*>(A + (size_t)gm * lda + kb + seg * 8);
      *reinterpret_cast<uint4*>(reinterpret_cast<char*>(Al) + off) = va;
      int gn = nBase + row;             // B rows always in-bounds (N multiple of 128)
      uint4 vb = *reinterpret_cast<const uint4*>(B + (size_t)gn * ldb + kb + seg * 8);
      *reinterpret_cast<uint4*>(reinterpret_cast<char*>(Bl) + off) = vb;
    }
    __syncthreads();
    #pragma unroll
    for (int ks = 0; ks < 2; ++ks){
      short8 a[4], b[4];
      #pragma unroll
      for (int f = 0; f < 4; ++f){
        int ra = wr * 64 + f * 16 + ln;
        int oa = (ra * 128 + ks * 64 + hi * 16) ^ ((ra & 7) << 4);
        a[f] = *reinterpret_cast<const short8*>(reinterpret_cast<const char*>(Al) + oa);
        int rb = wc * 64 + f * 16 + ln;
        int ob = (rb * 128 + ks * 64 + hi * 16) ^ ((rb & 7) << 4);
        b[f] = *reinterpret_cast<const short8*>(reinterpret_cast<const char*>(Bl) + ob);
      }
      #pragma unroll
      for (int fm = 0; fm < 4; ++fm)
        #pragma unroll
        for (int fn = 0; fn < 4; ++fn)
          acc[fm][fn] = __builtin_amdgcn_mfma_f32_16x16x32_bf16(a[fm], b[fn], acc[fm][fn], 0, 0, 0);
    }
  }
  #pragma unroll
  for (int fm = 0; fm < 4; ++fm){
    #pragma unroll
    for (int fn = 0; fn < 4; ++fn){
      int cg = nBase + wc * 64 + fn * 16 + ln;
      int r0 = mBase + wr * 64 + fm * 16 + hi * 4;
      f32x4 v = acc[fm][fn];
      #pragma unroll
      for (int j = 0; j < 4; ++j){
        int rg = r0 + j;
        if (rg < M) C[(size_t)rg * ldc + cg] = f2b(v[j]);
      }
    }
  }
}

// wave per node: out[n] = lrelu( h[n]*dinv[n]^2 + sum_in h[src]*dinv[src]*dinv[n] + bias )
// written as bf16 into H[:, cOff..cOff+128)
__global__ __launch_bounds__(256) void k_agg(
    const ushort* __restrict__ h, const float* __restrict__ dinv,
    const int* __restrict__ cnt, const int* __restrict__ col,
    const float* __restrict__ bias, ushort* __restrict__ H, int cOff){
  int lane = threadIdx.x & 63;
  int n = blockIdx.x * 4 + (threadIdx.x >> 6);
  if (n >= NN) return;
  float di = dinv[n];
  int f0 = lane * 2;
  ushort2 hv = *reinterpret_cast<const ushort2*>(h + (size_t)n * FD + f0);
  float a0 = b2f(hv.x) * di * di, a1 = b2f(hv.y) * di * di;
  int ne = cnt[n]; if (ne > MAXDEG) ne = MAXDEG;
  const int* cl = col + (size_t)n * MAXDEG;
  for (int j = 0; j < ne; ++j){
    int s = cl[j];
    float nr = dinv[s] * di;
    ushort2 hs = *reinterpret_cast<const ushort2*>(h + (size_t)s * FD + f0);
    a0 += b2f(hs.x) * nr; a1 += b2f(hs.y) * nr;
  }
  a0 += bias[f0]; a1 += bias[f0 + 1];
  a0 = a0 > 0.f ? a0 : 0.01f * a0;
  a1 = a1 > 0.f ? a1 : 0.01f * a1;
  ushort2 o; o.x = f2b(a0); o.y = f2b(a1);
  *reinterpret_cast<ushort2*>(H + (size_t)n * KH + cOff + f0) = o;
}

__global__ void k_hh(const ushort* __restrict__ H, float* __restrict__ hh){
  int lane = threadIdx.x & 63;
  int n = blockIdx.x * 4 + (threadIdx.x >> 6);
  if (n >= NN) return;
  const ushort* p = H + (size_t)n * KH + lane * 6;
  float s = 0.f;
  #pragma unroll
  for (int j = 0; j < 6; ++j){ float v = b2f(p[j]); s += v * v; }
  #pragma unroll
  for (int o = 32; o; o >>= 1) s += __shfl_down(s, o);
  if (lane == 0) hh[n] = s;
}

__global__ void k_ss(const float* __restrict__ S, float* __restrict__ ss){
  int u = blockIdx.x, lane = threadIdx.x;
  const float* p = S + (size_t)u * KH + lane * 6;
  float s = 0.f;
  #pragma unroll
  for (int j = 0; j < 6; ++j){ float v = p[j]; s += v * v; }
  #pragma unroll
  for (int o = 32; o; o >>= 1) s += __shfl_down(s, o);
  if (lane == 0) ss[u] = s;
}

// wave per run of 32 nodes; lane owns 4 lattice cells; register G accum, flush on batch change
__global__ __launch_bounds__(256) void k_som(
    const ushort* __restrict__ dots, const float* __restrict__ hh,
    const float* __restrict__ ss, const int* __restrict__ batch,
    float* __restrict__ G){
  int lane = threadIdx.x & 63;
  int gw = blockIdx.x * 4 + (threadIdx.x >> 6);
  int n0 = gw * 32;
  if (n0 >= NN) return;
  int n1 = min(n0 + 32, NN);
  float ssr[4];
  #pragma unroll
  for (int j = 0; j < 4; ++j) ssr[j] = ss[lane * 4 + j];
  float g[4] = {0.f, 0.f, 0.f, 0.f};
  int curb = batch[n0];
  for (int n = n0; n < n1; ++n){
    int b = batch[n];
    if (b != curb){
      #pragma unroll
      for (int j = 0; j < 4; ++j){ atomicAdd(&G[curb * NU + lane * 4 + j], g[j]); g[j] = 0.f; }
      curb = b;
    }
    ushort4 dv = *reinterpret_cast<const ushort4*>(dots + (size_t)n * NU + lane * 4);
    float v0 = ssr[0] - 2.f * b2f(dv.x);
    float v1 = ssr[1] - 2.f * b2f(dv.y);
    float v2 = ssr[2] - 2.f * b2f(dv.z);
    float v3 = ssr[3] - 2.f * b2f(dv.w);
    float mv = v0; int mi = lane * 4;
    if (v1 < mv){ mv = v1; mi = lane * 4 + 1; }
    if (v2 < mv){ mv = v2; mi = lane * 4 + 2; }
    if (v3 < mv){ mv = v3; mi = lane * 4 + 3; }
    #pragma unroll
    for (int o = 1; o < 64; o <<= 1){
      float ov = __shfl_xor(mv, o);
      int   oi = __shfl_xor(mi, o);
      if (ov < mv || (ov == mv && oi < mi)){ mv = ov; mi = oi; }
    }
    float d2 = fmaxf(hh[n] + mv, 0.f);
    float hsv = __expf(-sqrtf(d2));
    int wi = mi >> 4, wj = mi & 15;
    #pragma unroll
    for (int j = 0; j < 4; ++j){
      int c = lane * 4 + j;
      float dx = (float)((c >> 4) - wi), dy = (float)((c & 15) - wj);
      g[j] += hsv * __expf(-(dx * dx + dy * dy) * 0.125f);   // 1/(2*sigma^2), sigma=2
    }
  }
  #pragma unroll
  for (int j = 0; j < 4; ++j) atomicAdd(&G[curb * NU + lane * 4 + j], g[j]);
}

__global__ void k_out(const float* __restrict__ G, const float* __restrict__ lw,
                      const float* __restrict__ lb, float* __restrict__ out){
  int b = blockIdx.x, lane = threadIdx.x;
  float s = 0.f;
  #pragma unroll
  for (int j = 0; j < 4; ++j) s += G[b * NU + lane * 4 + j] * lw[lane * 4 + j];
  #pragma unroll
  for (int o = 32; o; o >>= 1) s += __shfl_down(s, o);
  if (lane == 0) out[b] = 1.f / (1.f + __expf(-(s + lb[0])));
}

extern "C" void kernel_launch(void* const* d_in, const int* in_sizes, int n_in,
                              void* d_out, int out_size, void* d_ws, size_t ws_size,
                              hipStream_t stream){
  const float* x   = (const float*)d_in[0];
  const int*   ei  = (const int*)d_in[1];
  const int*   bat = (const int*)d_in[2];
  const float* W1  = (const float*)d_in[3];
  const float* b1  = (const float*)d_in[4];
  const float* W2  = (const float*)d_in[5];
  const float* b2  = (const float*)d_in[6];
  const float* W3  = (const float*)d_in[7];
  const float* b3  = (const float*)d_in[8];
  const float* S   = (const float*)d_in[9];
  const float* lw  = (const float*)d_in[10];
  const float* lb  = (const float*)d_in[11];
  float* out = (float*)d_out;
  char* w = (char*)d_ws;

  int*    cnt  = (int*)   (w + OFF_CNT);
  float*  G    = (float*) (w + OFF_G);
  int*    col  = (int*)   (w + OFF_COL);
  float*  dinv = (float*) (w + OFF_DINV);
  ushort* xbf  = (ushort*)(w + OFF_XBF);
  ushort* hbf  = (ushort*)(w + OFF_HBF);
  ushort* H    = (ushort*)(w + OFF_H);
  float*  hh   = (float*) (w + OFF_HH);
  ushort* dots = (ushort*)(w + OFF_DOTS);
  ushort* Wt   = (ushort*)(w + OFF_WT);
  ushort* Sbf  = (ushort*)(w + OFF_SBF);
  float*  ss   = (float*) (w + OFF_SS);

  hipMemsetAsync(w, 0, 265536, stream);                     // cnt + G

  k_convert<<<6250, 256, 0, stream>>>(x, xbf, 1600000);     // x -> bf16
  k_convert<<<96,   256, 0, stream>>>(S, Sbf, 24576);       // S -> bf16 ([256][384])
  k_twc<<<128, 128, 0, stream>>>(W1, Wt);
  k_twc<<<128, 128, 0, stream>>>(W2, Wt + 16384);
  k_twc<<<128, 128, 0, stream>>>(W3, Wt + 32768);

  k_count<<<3125, 256, 0, stream>>>(ei, cnt);
  k_dinv<<<196, 256, 0, stream>>>(cnt, dinv);
  k_scatter<<<3125, 256, 0, stream>>>(ei, cnt, col);

  dim3 blk(256);
  // layer 1
  k_gemm<<<dim3(391, 1), blk, 0, stream>>>(xbf, FD, Wt, FD, hbf, FD, NN, FD);
  k_agg<<<12500, 256, 0, stream>>>(hbf, dinv, cnt, col, b1, H, 0);
  // layer 2 (input = H[:,0:128))
  k_gemm<<<dim3(391, 1), blk, 0, stream>>>(H, KH, Wt + 16384, FD, hbf, FD, NN, FD);
  k_agg<<<12500, 256, 0, stream>>>(hbf, dinv, cnt, col, b2, H, 128);
  // layer 3 (input = H[:,128:256))
  k_gemm<<<dim3(391, 1), blk, 0, stream>>>(H + 128, KH, Wt + 32768, FD, hbf, FD, NN, FD);
  k_agg<<<12500, 256, 0, stream>>>(hbf, dinv, cnt, col, b3, H, 256);

  k_hh<<<12500, 256, 0, stream>>>(H, hh);
  k_ss<<<256, 64, 0, stream>>>(S, ss);
  // SOM dot GEMM: dots[N][256] = H[N][384] @ Sbf[256][384]^T
  k_gemm<<<dim3(391, 2), blk, 0, stream>>>(H, KH, Sbf, KH, dots, NU, NN, KH);
  k_som<<<391, 256, 0, stream>>>(dots, hh, ss, bat, G);
  k_out<<<64, 64, 0, stream>>>(G, lw, lb, out);
}

// Round 2
// 362.721 us; speedup vs baseline: 1.2967x; 1.2967x over previous
//
#include <hip/hip_runtime.h>

#define NN 50000
#define NE 800000
#define FD 128
#define KH 384
#define NU 256
#define NG 64
#define MAXDEG 64

typedef __attribute__((__ext_vector_type__(8))) short short8;
typedef __attribute__((__ext_vector_type__(4))) float f32x4;

// ---- ws layout (bytes, all offsets 16B-aligned) ----
#define OFF_CNT   0u           // NN int            (200000)
#define OFF_G     200000u      // 64*256 f32        (65536)   zeroed with cnt
#define OFF_COL   265536u      // NN*MAXDEG int     (12800000)
#define OFF_DINV  13065536u    // NN f32            (200000)
#define OFF_XBF   13265536u    // NN*128 bf16       (12800000)
#define OFF_HBF   26065536u    // NN*128 bf16       (12800000)
#define OFF_H     38865536u    // NN*384 bf16       (38400000)
#define OFF_HH    77265536u    // NN f32            (200000)
#define OFF_DOTS  77465536u    // NN*256 bf16       (25600000)
#define OFF_WT    103065536u   // 3*128*128 bf16    (98304)
#define OFF_SBF   103163840u   // 256*384 bf16      (196608)
#define OFF_SS    103360448u   // 256 f32           (1024)  -> total 103361472

__device__ __forceinline__ float b2f(ushort h){
  union { unsigned u; float f; } c; c.u = ((unsigned)h) << 16; return c.f;
}
__device__ __forceinline__ ushort f2b(float f){
  union { float f; unsigned u; } c; c.f = f;
  unsigned u = c.u;
  return (ushort)((u + 0x7fffu + ((u >> 16) & 1u)) >> 16);
}

__global__ void k_convert(const float* __restrict__ s, ushort* __restrict__ d, int n4){
  int i = blockIdx.x * blockDim.x + threadIdx.x;
  if (i >= n4) return;
  float4 v = reinterpret_cast<const float4*>(s)[i];
  ushort4 o; o.x = f2b(v.x); o.y = f2b(v.y); o.z = f2b(v.z); o.w = f2b(v.w);
  reinterpret_cast<ushort4*>(d)[i] = o;
}

// Wt[n][k] = bf16(W[k][n])  (block = n, thread = k)
__global__ void k_twc(const float* __restrict__ W, ushort* __restrict__ Wt){
  int n = blockIdx.x, k = threadIdx.x;
  Wt[n * FD + k] = f2b(W[k * FD + n]);
}

__global__ void k_count(const int* __restrict__ ei, int* __restrict__ cnt){
  int e = blockIdx.x * blockDim.x + threadIdx.x;
  if (e < NE) atomicAdd(&cnt[ei[NE + e]], 1);
}

__global__ void k_dinv(int* __restrict__ cnt, float* __restrict__ dinv){
  int i = blockIdx.x * blockDim.x + threadIdx.x;
  if (i < NN){ dinv[i] = rsqrtf((float)(cnt[i] + 1)); cnt[i] = 0; }
}

__global__ void k_scatter(const int* __restrict__ ei, int* __restrict__ cnt, int* __restrict__ col){
  int e = blockIdx.x * blockDim.x + threadIdx.x;
  if (e >= NE) return;
  int d = ei[NE + e];
  int pos = atomicAdd(&cnt[d], 1);
  if (pos < MAXDEG) col[(size_t)d * MAXDEG + pos] = ei[e];
}

// C[M][Nt] = A[M][K] * B_T[Nt][K]^T   (all bf16, fp32 accum, bf16 out)
// tile 128x128, BK=64, 4 waves (2x2), mfma_f32_16x16x32_bf16, XOR-swizzled LDS
__global__ __launch_bounds__(256) void k_gemm(
    const ushort* __restrict__ A, int lda,
    const ushort* __restrict__ B, int ldb,
    ushort* __restrict__ C, int ldc, int M, int K){
  __shared__ __align__(16) ushort Al[128 * 64];
  __shared__ __align__(16) ushort Bl[128 * 64];
  const int t = threadIdx.x;
  const int lane = t & 63, w = t >> 6;
  const int wr = w >> 1, wc = w & 1;
  const int ln = lane & 15, hi = lane >> 4;
  const int mBase = blockIdx.x * 128, nBase = blockIdx.y * 128;

  f32x4 zero = {0.f, 0.f, 0.f, 0.f};
  f32x4 acc[4][4];
  #pragma unroll
  for (int i = 0; i < 4; ++i)
    #pragma unroll
    for (int j = 0; j < 4; ++j) acc[i][j] = zero;

  for (int kb = 0; kb < K; kb += 64){
    __syncthreads();
    #pragma unroll
    for (int it = 0; it < 4; ++it){
      int idx = t + it * 256;           // 0..1023
      int row = idx >> 3, seg = idx & 7;
      int off = (row * 128 + seg * 16) ^ ((row & 7) << 4);
      uint4 va = make_uint4(0u, 0u, 0u, 0u);
      int gm = mBase + row;
      if (gm < M) va = *reinterpret_cast<const uint4*>(A + (size_t)gm * lda + kb + seg * 8);
      *reinterpret_cast<uint4*>(reinterpret_cast<char*>(Al) + off) = va;
      int gn = nBase + row;             // B rows always in-bounds (N multiple of 128)
      uint4 vb = *reinterpret_cast<const uint4*>(B + (size_t)gn * ldb + kb + seg * 8);
      *reinterpret_cast<uint4*>(reinterpret_cast<char*>(Bl) + off) = vb;
    }
    __syncthreads();
    #pragma unroll
    for (int ks = 0; ks < 2; ++ks){
      short8 a[4], b[4];
      #pragma unroll
      for (int f = 0; f < 4; ++f){
        int ra = wr * 64 + f * 16 + ln;
        int oa = (ra * 128 + ks * 64 + hi * 16) ^ ((ra & 7) << 4);
        a[f] = *reinterpret_cast<const short8*>(reinterpret_cast<const char*>(Al) + oa);
        int rb = wc * 64 + f * 16 + ln;
        int ob = (rb * 128 + ks * 64 + hi * 16) ^ ((rb & 7) << 4);
        b[f] = *reinterpret_cast<const short8*>(reinterpret_cast<const char*>(Bl) + ob);
      }
      #pragma unroll
      for (int fm = 0; fm < 4; ++fm)
        #pragma unroll
        for (int fn = 0; fn < 4; ++fn)
          acc[fm][fn] = __builtin_amdgcn_mfma_f32_16x16x32_bf16(a[fm], b[fn], acc[fm][fn], 0, 0, 0);
    }
  }
  #pragma unroll
  for (int fm = 0; fm < 4; ++fm){
    #pragma unroll
    for (int fn = 0; fn < 4; ++fn){
      int cg = nBase + wc * 64 + fn * 16 + ln;
      int r0 = mBase + wr * 64 + fm * 16 + hi * 4;
      f32x4 v = acc[fm][fn];
      #pragma unroll
      for (int j = 0; j < 4; ++j){
        int rg = r0 + j;
        if (rg < M) C[(size_t)rg * ldc + cg] = f2b(v[j]);
      }
    }
  }
}

// wave per node, 4 groups x 16 lanes. group g handles neighbors j+g; lane owns 8 features.
// 8 neighbor rows (2KB) in flight per iteration. Fuses sum-of-squares (hh).
__global__ __launch_bounds__(256) void k_agg(
    const ushort* __restrict__ h, const float* __restrict__ dinv,
    const int* __restrict__ cnt, const int* __restrict__ col,
    const float* __restrict__ bias, ushort* __restrict__ H, int cOff,
    float* __restrict__ hh){
  int lane = threadIdx.x & 63;
  int n = blockIdx.x * 4 + (threadIdx.x >> 6);
  if (n >= NN) return;
  const int g = lane >> 4, ln = lane & 15;
  const int f0 = ln * 8;
  float di = dinv[n];
  float acc[8] = {0.f,0.f,0.f,0.f,0.f,0.f,0.f,0.f};
  if (g == 0){                     // self loop (added once)
    short8 hv = *reinterpret_cast<const short8*>(h + (size_t)n * FD + f0);
    float dd = di * di;
    #pragma unroll
    for (int k = 0; k < 8; ++k) acc[k] = b2f((ushort)hv[k]) * dd;
  }
  int ne = cnt[n]; if (ne > MAXDEG) ne = MAXDEG;
  const int* cl = col + (size_t)n * MAXDEG;
  for (int j = 0; j < ne; j += 8){
    int j0 = j + g, j1 = j + 4 + g;
    int s0 = 0, s1 = 0; float nr0 = 0.f, nr1 = 0.f;
    if (j0 < ne){ s0 = cl[j0]; nr0 = dinv[s0] * di; }
    if (j1 < ne){ s1 = cl[j1]; nr1 = dinv[s1] * di; }
    short8 h0 = *reinterpret_cast<const short8*>(h + (size_t)s0 * FD + f0);
    short8 h1 = *reinterpret_cast<const short8*>(h + (size_t)s1 * FD + f0);
    #pragma unroll
    for (int k = 0; k < 8; ++k) acc[k] += b2f((ushort)h0[k]) * nr0;
    #pragma unroll
    for (int k = 0; k < 8; ++k) acc[k] += b2f((ushort)h1[k]) * nr1;
  }
  // combine the 4 groups
  #pragma unroll
  for (int k = 0; k < 8; ++k){
    acc[k] += __shfl_xor(acc[k], 16);
    acc[k] += __shfl_xor(acc[k], 32);
  }
  // bias + leaky-relu + sum of squares
  float ssq = 0.f;
  short8 o;
  #pragma unroll
  for (int k = 0; k < 8; ++k){
    float v = acc[k] + bias[f0 + k];
    v = v > 0.f ? v : 0.01f * v;
    ssq += v * v;
    o[k] = (short)f2b(v);
  }
  if (g == 0){
    *reinterpret_cast<short8*>(H + (size_t)n * KH + cOff + f0) = o;
    // reduce ssq over the 16 lanes of group 0
    #pragma unroll
    for (int m = 1; m < 16; m <<= 1) ssq += __shfl_xor(ssq, m);
    if (ln == 0){
      if (cOff == 0) hh[n] = ssq;
      else           hh[n] += ssq;
    }
  }
}

__global__ void k_ss(const float* __restrict__ S, float* __restrict__ ss){
  int u = blockIdx.x, lane = threadIdx.x;
  const float* p = S + (size_t)u * KH + lane * 6;
  float s = 0.f;
  #pragma unroll
  for (int j = 0; j < 6; ++j){ float v = p[j]; s += v * v; }
  #pragma unroll
  for (int o = 32; o; o >>= 1) s += __shfl_down(s, o);
  if (lane == 0) ss[u] = s;
}

// wave per run of 32 nodes; lane owns 4 lattice cells; register G accum, flush on batch change
__global__ __launch_bounds__(256) void k_som(
    const ushort* __restrict__ dots, const float* __restrict__ hh,
    const float* __restrict__ ss, const int* __restrict__ batch,
    float* __restrict__ G){
  int lane = threadIdx.x & 63;
  int gw = blockIdx.x * 4 + (threadIdx.x >> 6);
  int n0 = gw * 32;
  if (n0 >= NN) return;
  int n1 = min(n0 + 32, NN);
  float ssr[4];
  #pragma unroll
  for (int j = 0; j < 4; ++j) ssr[j] = ss[lane * 4 + j];
  float g[4] = {0.f, 0.f, 0.f, 0.f};
  int curb = batch[n0];
  for (int n = n0; n < n1; ++n){
    int b = batch[n];
    if (b != curb){
      #pragma unroll
      for (int j = 0; j < 4; ++j){ atomicAdd(&G[curb * NU + lane * 4 + j], g[j]); g[j] = 0.f; }
      curb = b;
    }
    ushort4 dv = *reinterpret_cast<const ushort4*>(dots + (size_t)n * NU + lane * 4);
    float v0 = ssr[0] - 2.f * b2f(dv.x);
    float v1 = ssr[1] - 2.f * b2f(dv.y);
    float v2 = ssr[2] - 2.f * b2f(dv.z);
    float v3 = ssr[3] - 2.f * b2f(dv.w);
    float mv = v0; int mi = lane * 4;
    if (v1 < mv){ mv = v1; mi = lane * 4 + 1; }
    if (v2 < mv){ mv = v2; mi = lane * 4 + 2; }
    if (v3 < mv){ mv = v3; mi = lane * 4 + 3; }
    #pragma unroll
    for (int o = 1; o < 64; o <<= 1){
      float ov = __shfl_xor(mv, o);
      int   oi = __shfl_xor(mi, o);
      if (ov < mv || (ov == mv && oi < mi)){ mv = ov; mi = oi; }
    }
    float d2 = fmaxf(hh[n] + mv, 0.f);
    float hsv = __expf(-sqrtf(d2));
    int wi = mi >> 4, wj = mi & 15;
    #pragma unroll
    for (int j = 0; j < 4; ++j){
      int c = lane * 4 + j;
      float dx = (float)((c >> 4) - wi), dy = (float)((c & 15) - wj);
      g[j] += hsv * __expf(-(dx * dx + dy * dy) * 0.125f);   // 1/(2*sigma^2), sigma=2
    }
  }
  #pragma unroll
  for (int j = 0; j < 4; ++j) atomicAdd(&G[curb * NU + lane * 4 + j], g[j]);
}

__global__ void k_out(const float* __restrict__ G, const float* __restrict__ lw,
                      const float* __restrict__ lb, float* __restrict__ out){
  int b = blockIdx.x, lane = threadIdx.x;
  float s = 0.f;
  #pragma unroll
  for (int j = 0; j < 4; ++j) s += G[b * NU + lane * 4 + j] * lw[lane * 4 + j];
  #pragma unroll
  for (int o = 32; o; o >>= 1) s += __shfl_down(s, o);
  if (lane == 0) out[b] = 1.f / (1.f + __expf(-(s + lb[0])));
}

extern "C" void kernel_launch(void* const* d_in, const int* in_sizes, int n_in,
                              void* d_out, int out_size, void* d_ws, size_t ws_size,
                              hipStream_t stream){
  const float* x   = (const float*)d_in[0];
  const int*   ei  = (const int*)d_in[1];
  const int*   bat = (const int*)d_in[2];
  const float* W1  = (const float*)d_in[3];
  const float* b1  = (const float*)d_in[4];
  const float* W2  = (const float*)d_in[5];
  const float* b2  = (const float*)d_in[6];
  const float* W3  = (const float*)d_in[7];
  const float* b3  = (const float*)d_in[8];
  const float* S   = (const float*)d_in[9];
  const float* lw  = (const float*)d_in[10];
  const float* lb  = (const float*)d_in[11];
  float* out = (float*)d_out;
  char* w = (char*)d_ws;

  int*    cnt  = (int*)   (w + OFF_CNT);
  float*  G    = (float*) (w + OFF_G);
  int*    col  = (int*)   (w + OFF_COL);
  float*  dinv = (float*) (w + OFF_DINV);
  ushort* xbf  = (ushort*)(w + OFF_XBF);
  ushort* hbf  = (ushort*)(w + OFF_HBF);
  ushort* H    = (ushort*)(w + OFF_H);
  float*  hh   = (float*) (w + OFF_HH);
  ushort* dots = (ushort*)(w + OFF_DOTS);
  ushort* Wt   = (ushort*)(w + OFF_WT);
  ushort* Sbf  = (ushort*)(w + OFF_SBF);
  float*  ss   = (float*) (w + OFF_SS);

  hipMemsetAsync(w, 0, 265536, stream);                     // cnt + G

  k_convert<<<6250, 256, 0, stream>>>(x, xbf, 1600000);     // x -> bf16
  k_convert<<<96,   256, 0, stream>>>(S, Sbf, 24576);       // S -> bf16 ([256][384])
  k_twc<<<128, 128, 0, stream>>>(W1, Wt);
  k_twc<<<128, 128, 0, stream>>>(W2, Wt + 16384);
  k_twc<<<128, 128, 0, stream>>>(W3, Wt + 32768);

  k_count<<<3125, 256, 0, stream>>>(ei, cnt);
  k_dinv<<<196, 256, 0, stream>>>(cnt, dinv);
  k_scatter<<<3125, 256, 0, stream>>>(ei, cnt, col);

  dim3 blk(256);
  // layer 1
  k_gemm<<<dim3(391, 1), blk, 0, stream>>>(xbf, FD, Wt, FD, hbf, FD, NN, FD);
  k_agg<<<12500, 256, 0, stream>>>(hbf, dinv, cnt, col, b1, H, 0, hh);
  // layer 2 (input = H[:,0:128))
  k_gemm<<<dim3(391, 1), blk, 0, stream>>>(H, KH, Wt + 16384, FD, hbf, FD, NN, FD);
  k_agg<<<12500, 256, 0, stream>>>(hbf, dinv, cnt, col, b2, H, 128, hh);
  // layer 3 (input = H[:,128:256))
  k_gemm<<<dim3(391, 1), blk, 0, stream>>>(H + 128, KH, Wt + 32768, FD, hbf, FD, NN, KH == 384 ? FD : FD);
  k_agg<<<12500, 256, 0, stream>>>(hbf, dinv, cnt, col, b3, H, 256, hh);

  k_ss<<<256, 64, 0, stream>>>(S, ss);
  // SOM dot GEMM: dots[N][256] = H[N][384] @ Sbf[256][384]^T
  k_gemm<<<dim3(391, 2), blk, 0, stream>>>(H, KH, Sbf, KH, dots, NU, NN, KH);
  k_som<<<391, 256, 0, stream>>>(dots, hh, ss, bat, G);
  k_out<<<64, 64, 0, stream>>>(G, lw, lb, out);
}

// Round 3
// 316.025 us; speedup vs baseline: 1.4883x; 1.1478x over previous
//
#include <hip/hip_runtime.h>

#define NN 50000
#define NE 800000
#define FD 128
#define KH 384
#define NU 256
#define NG 64
#define MAXDEG 64

typedef __attribute__((__ext_vector_type__(8))) short short8;
typedef __attribute__((__ext_vector_type__(4))) float f32x4;

// ---- ws layout (bytes, all offsets 16B-aligned) ----
#define OFF_CNT   0u           // NN int            (200000)
#define OFF_G     200000u      // 64*256 f32        (65536)   zeroed with cnt
#define OFF_COL   265536u      // NN*MAXDEG int     (12800000)
#define OFF_DINV  13065536u    // NN f32            (200000)
#define OFF_XBF   13265536u    // NN*128 bf16       (12800000)
#define OFF_HBF   26065536u    // NN*128 bf16       (12800000)
#define OFF_H     38865536u    // NN*384 bf16       (38400000)
#define OFF_HH    77265536u    // NN f32            (200000)
#define OFF_DOTS  77465536u    // NN*256 bf16       (25600000)
#define OFF_WT    103065536u   // 3*128*128 bf16    (98304)
#define OFF_SBF   103163840u   // 256*384 bf16      (196608)
#define OFF_SS    103360448u   // 256 f32           (1024)  -> total 103361472

__device__ __forceinline__ float b2f(ushort h){
  union { unsigned u; float f; } c; c.u = ((unsigned)h) << 16; return c.f;
}
__device__ __forceinline__ ushort f2b(float f){
  union { float f; unsigned u; } c; c.f = f;
  unsigned u = c.u;
  return (ushort)((u + 0x7fffu + ((u >> 16) & 1u)) >> 16);
}

__global__ void k_convert(const float* __restrict__ s, ushort* __restrict__ d, int n4){
  int i = blockIdx.x * blockDim.x + threadIdx.x;
  if (i >= n4) return;
  float4 v = reinterpret_cast<const float4*>(s)[i];
  ushort4 o; o.x = f2b(v.x); o.y = f2b(v.y); o.z = f2b(v.z); o.w = f2b(v.w);
  reinterpret_cast<ushort4*>(d)[i] = o;
}

// Wt[n][k] = bf16(W[k][n])  (block = n, thread = k)
__global__ void k_twc(const float* __restrict__ W, ushort* __restrict__ Wt){
  int n = blockIdx.x, k = threadIdx.x;
  Wt[n * FD + k] = f2b(W[k * FD + n]);
}

// merged count+scatter: cnt ends up holding the in-degree (excl self loop)
__global__ void k_scatter(const int* __restrict__ ei, int* __restrict__ cnt, int* __restrict__ col){
  int e = blockIdx.x * blockDim.x + threadIdx.x;
  if (e >= NE) return;
  int d = ei[NE + e];
  int pos = atomicAdd(&cnt[d], 1);
  if (pos < MAXDEG) col[(size_t)d * MAXDEG + pos] = ei[e];
}

__global__ void k_dinv(const int* __restrict__ cnt, float* __restrict__ dinv){
  int i = blockIdx.x * blockDim.x + threadIdx.x;
  if (i < NN) dinv[i] = rsqrtf((float)(cnt[i] + 1));
}

// C[M][Nt] = A[M][K] * B_T[Nt][K]^T   (all bf16, fp32 accum, bf16 out)
// optional epilogue row scale: C[r][c] = (acc * rs[r]) if rs != nullptr
__global__ __launch_bounds__(256) void k_gemm(
    const ushort* __restrict__ A, int lda,
    const ushort* __restrict__ B, int ldb,
    ushort* __restrict__ C, int ldc, int M, int K,
    const float* __restrict__ rs){
  __shared__ __align__(16) ushort Al[128 * 64];
  __shared__ __align__(16) ushort Bl[128 * 64];
  const int t = threadIdx.x;
  const int lane = t & 63, w = t >> 6;
  const int wr = w >> 1, wc = w & 1;
  const int ln = lane & 15, hi = lane >> 4;
  const int mBase = blockIdx.x * 128, nBase = blockIdx.y * 128;

  f32x4 zero = {0.f, 0.f, 0.f, 0.f};
  f32x4 acc[4][4];
  #pragma unroll
  for (int i = 0; i < 4; ++i)
    #pragma unroll
    for (int j = 0; j < 4; ++j) acc[i][j] = zero;

  for (int kb = 0; kb < K; kb += 64){
    __syncthreads();
    #pragma unroll
    for (int it = 0; it < 4; ++it){
      int idx = t + it * 256;           // 0..1023
      int row = idx >> 3, seg = idx & 7;
      int off = (row * 128 + seg * 16) ^ ((row & 7) << 4);
      uint4 va = make_uint4(0u, 0u, 0u, 0u);
      int gm = mBase + row;
      if (gm < M) va = *reinterpret_cast<const uint4*>(A + (size_t)gm * lda + kb + seg * 8);
      *reinterpret_cast<uint4*>(reinterpret_cast<char*>(Al) + off) = va;
      int gn = nBase + row;             // B rows always in-bounds (N multiple of 128)
      uint4 vb = *reinterpret_cast<const uint4*>(B + (size_t)gn * ldb + kb + seg * 8);
      *reinterpret_cast<uint4*>(reinterpret_cast<char*>(Bl) + off) = vb;
    }
    __syncthreads();
    #pragma unroll
    for (int ks = 0; ks < 2; ++ks){
      short8 a[4], b[4];
      #pragma unroll
      for (int f = 0; f < 4; ++f){
        int ra = wr * 64 + f * 16 + ln;
        int oa = (ra * 128 + ks * 64 + hi * 16) ^ ((ra & 7) << 4);
        a[f] = *reinterpret_cast<const short8*>(reinterpret_cast<const char*>(Al) + oa);
        int rb = wc * 64 + f * 16 + ln;
        int ob = (rb * 128 + ks * 64 + hi * 16) ^ ((rb & 7) << 4);
        b[f] = *reinterpret_cast<const short8*>(reinterpret_cast<const char*>(Bl) + ob);
      }
      #pragma unroll
      for (int fm = 0; fm < 4; ++fm)
        #pragma unroll
        for (int fn = 0; fn < 4; ++fn)
          acc[fm][fn] = __builtin_amdgcn_mfma_f32_16x16x32_bf16(a[fm], b[fn], acc[fm][fn], 0, 0, 0);
    }
  }
  #pragma unroll
  for (int fm = 0; fm < 4; ++fm){
    int r0 = mBase + wr * 64 + fm * 16 + hi * 4;
    float rsv[4] = {1.f, 1.f, 1.f, 1.f};
    if (rs){
      #pragma unroll
      for (int j = 0; j < 4; ++j) if (r0 + j < M) rsv[j] = rs[r0 + j];
    }
    #pragma unroll
    for (int fn = 0; fn < 4; ++fn){
      int cg = nBase + wc * 64 + fn * 16 + ln;
      f32x4 v = acc[fm][fn];
      #pragma unroll
      for (int j = 0; j < 4; ++j){
        int rg = r0 + j;
        if (rg < M) C[(size_t)rg * ldc + cg] = f2b(v[j] * rsv[j]);
      }
    }
  }
}

// wave per node, 4 groups x 16 lanes; lane owns 8 features (16B rows).
// input hs is PRE-SCALED by dinv (done in GEMM epilogue):
//   out[n] = lrelu( dinv[n] * (hs[n] + sum_j hs[col[j]]) + bias )
// 16 neighbors (4KB) in flight per iteration. Fuses sum-of-squares (hh).
__global__ __launch_bounds__(256) void k_agg(
    const ushort* __restrict__ hs, const float* __restrict__ dinv,
    const int* __restrict__ cnt, const int* __restrict__ col,
    const float* __restrict__ bias, ushort* __restrict__ H, int cOff,
    float* __restrict__ hh){
  int lane = threadIdx.x & 63;
  int n = blockIdx.x * 4 + (threadIdx.x >> 6);
  if (n >= NN) return;
  const int g = lane >> 4, ln = lane & 15;
  const int f0 = ln * 8;
  float acc[8] = {0.f,0.f,0.f,0.f,0.f,0.f,0.f,0.f};
  if (g == 0){                     // self loop
    short8 hv = *reinterpret_cast<const short8*>(hs + (size_t)n * FD + f0);
    #pragma unroll
    for (int k = 0; k < 8; ++k) acc[k] = b2f((ushort)hv[k]);
  }
  int ne = cnt[n]; if (ne > MAXDEG) ne = MAXDEG;
  const int* cl = col + (size_t)n * MAXDEG;
  for (int j = 0; j < ne; j += 16){
    int i0 = j + g, i1 = j + 4 + g, i2 = j + 8 + g, i3 = j + 12 + g;
    int s0 = n, s1 = n, s2 = n, s3 = n;
    float w0 = 0.f, w1 = 0.f, w2 = 0.f, w3 = 0.f;
    if (i0 < ne){ s0 = cl[i0]; w0 = 1.f; }
    if (i1 < ne){ s1 = cl[i1]; w1 = 1.f; }
    if (i2 < ne){ s2 = cl[i2]; w2 = 1.f; }
    if (i3 < ne){ s3 = cl[i3]; w3 = 1.f; }
    short8 h0 = *reinterpret_cast<const short8*>(hs + (size_t)s0 * FD + f0);
    short8 h1 = *reinterpret_cast<const short8*>(hs + (size_t)s1 * FD + f0);
    short8 h2 = *reinterpret_cast<const short8*>(hs + (size_t)s2 * FD + f0);
    short8 h3 = *reinterpret_cast<const short8*>(hs + (size_t)s3 * FD + f0);
    #pragma unroll
    for (int k = 0; k < 8; ++k) acc[k] += b2f((ushort)h0[k]) * w0;
    #pragma unroll
    for (int k = 0; k < 8; ++k) acc[k] += b2f((ushort)h1[k]) * w1;
    #pragma unroll
    for (int k = 0; k < 8; ++k) acc[k] += b2f((ushort)h2[k]) * w2;
    #pragma unroll
    for (int k = 0; k < 8; ++k) acc[k] += b2f((ushort)h3[k]) * w3;
  }
  // combine the 4 groups
  #pragma unroll
  for (int k = 0; k < 8; ++k){
    acc[k] += __shfl_xor(acc[k], 16);
    acc[k] += __shfl_xor(acc[k], 32);
  }
  // scale + bias + leaky-relu + sum of squares
  float di = dinv[n];
  float ssq = 0.f;
  short8 o;
  #pragma unroll
  for (int k = 0; k < 8; ++k){
    float v = acc[k] * di + bias[f0 + k];
    v = v > 0.f ? v : 0.01f * v;
    ssq += v * v;
    o[k] = (short)f2b(v);
  }
  if (g == 0){
    *reinterpret_cast<short8*>(H + (size_t)n * KH + cOff + f0) = o;
    #pragma unroll
    for (int m = 1; m < 16; m <<= 1) ssq += __shfl_xor(ssq, m);
    if (ln == 0){
      if (cOff == 0) hh[n] = ssq;
      else           hh[n] += ssq;
    }
  }
}

__global__ void k_ss(const float* __restrict__ S, float* __restrict__ ss){
  int u = blockIdx.x, lane = threadIdx.x;
  const float* p = S + (size_t)u * KH + lane * 6;
  float s = 0.f;
  #pragma unroll
  for (int j = 0; j < 6; ++j){ float v = p[j]; s += v * v; }
  #pragma unroll
  for (int o = 32; o; o >>= 1) s += __shfl_down(s, o);
  if (lane == 0) ss[u] = s;
}

// wave per run of 32 nodes; lane owns 4 lattice cells; register G accum, flush on batch change
__global__ __launch_bounds__(256) void k_som(
    const ushort* __restrict__ dots, const float* __restrict__ hh,
    const float* __restrict__ ss, const int* __restrict__ batch,
    float* __restrict__ G){
  int lane = threadIdx.x & 63;
  int gw = blockIdx.x * 4 + (threadIdx.x >> 6);
  int n0 = gw * 32;
  if (n0 >= NN) return;
  int n1 = min(n0 + 32, NN);
  float ssr[4];
  #pragma unroll
  for (int j = 0; j < 4; ++j) ssr[j] = ss[lane * 4 + j];
  float g[4] = {0.f, 0.f, 0.f, 0.f};
  int curb = batch[n0];
  for (int n = n0; n < n1; ++n){
    int b = batch[n];
    if (b != curb){
      #pragma unroll
      for (int j = 0; j < 4; ++j){ atomicAdd(&G[curb * NU + lane * 4 + j], g[j]); g[j] = 0.f; }
      curb = b;
    }
    ushort4 dv = *reinterpret_cast<const ushort4*>(dots + (size_t)n * NU + lane * 4);
    float v0 = ssr[0] - 2.f * b2f(dv.x);
    float v1 = ssr[1] - 2.f * b2f(dv.y);
    float v2 = ssr[2] - 2.f * b2f(dv.z);
    float v3 = ssr[3] - 2.f * b2f(dv.w);
    float mv = v0; int mi = lane * 4;
    if (v1 < mv){ mv = v1; mi = lane * 4 + 1; }
    if (v2 < mv){ mv = v2; mi = lane * 4 + 2; }
    if (v3 < mv){ mv = v3; mi = lane * 4 + 3; }
    #pragma unroll
    for (int o = 1; o < 64; o <<= 1){
      float ov = __shfl_xor(mv, o);
      int   oi = __shfl_xor(mi, o);
      if (ov < mv || (ov == mv && oi < mi)){ mv = ov; mi = oi; }
    }
    float d2 = fmaxf(hh[n] + mv, 0.f);
    float hsv = __expf(-sqrtf(d2));
    int wi = mi >> 4, wj = mi & 15;
    #pragma unroll
    for (int j = 0; j < 4; ++j){
      int c = lane * 4 + j;
      float dx = (float)((c >> 4) - wi), dy = (float)((c & 15) - wj);
      g[j] += hsv * __expf(-(dx * dx + dy * dy) * 0.125f);   // 1/(2*sigma^2), sigma=2
    }
  }
  #pragma unroll
  for (int j = 0; j < 4; ++j) atomicAdd(&G[curb * NU + lane * 4 + j], g[j]);
}

__global__ void k_out(const float* __restrict__ G, const float* __restrict__ lw,
                      const float* __restrict__ lb, float* __restrict__ out){
  int b = blockIdx.x, lane = threadIdx.x;
  float s = 0.f;
  #pragma unroll
  for (int j = 0; j < 4; ++j) s += G[b * NU + lane * 4 + j] * lw[lane * 4 + j];
  #pragma unroll
  for (int o = 32; o; o >>= 1) s += __shfl_down(s, o);
  if (lane == 0) out[b] = 1.f / (1.f + __expf(-(s + lb[0])));
}

extern "C" void kernel_launch(void* const* d_in, const int* in_sizes, int n_in,
                              void* d_out, int out_size, void* d_ws, size_t ws_size,
                              hipStream_t stream){
  const float* x   = (const float*)d_in[0];
  const int*   ei  = (const int*)d_in[1];
  const int*   bat = (const int*)d_in[2];
  const float* W1  = (const float*)d_in[3];
  const float* b1  = (const float*)d_in[4];
  const float* W2  = (const float*)d_in[5];
  const float* b2  = (const float*)d_in[6];
  const float* W3  = (const float*)d_in[7];
  const float* b3  = (const float*)d_in[8];
  const float* S   = (const float*)d_in[9];
  const float* lw  = (const float*)d_in[10];
  const float* lb  = (const float*)d_in[11];
  float* out = (float*)d_out;
  char* w = (char*)d_ws;

  int*    cnt  = (int*)   (w + OFF_CNT);
  float*  G    = (float*) (w + OFF_G);
  int*    col  = (int*)   (w + OFF_COL);
  float*  dinv = (float*) (w + OFF_DINV);
  ushort* xbf  = (ushort*)(w + OFF_XBF);
  ushort* hbf  = (ushort*)(w + OFF_HBF);
  ushort* H    = (ushort*)(w + OFF_H);
  float*  hh   = (float*) (w + OFF_HH);
  ushort* dots = (ushort*)(w + OFF_DOTS);
  ushort* Wt   = (ushort*)(w + OFF_WT);
  ushort* Sbf  = (ushort*)(w + OFF_SBF);
  float*  ss   = (float*) (w + OFF_SS);

  hipMemsetAsync(w, 0, 265536, stream);                     // cnt + G

  k_convert<<<6250, 256, 0, stream>>>(x, xbf, 1600000);     // x -> bf16
  k_convert<<<96,   256, 0, stream>>>(S, Sbf, 24576);       // S -> bf16 ([256][384])
  k_twc<<<128, 128, 0, stream>>>(W1, Wt);
  k_twc<<<128, 128, 0, stream>>>(W2, Wt + 16384);
  k_twc<<<128, 128, 0, stream>>>(W3, Wt + 32768);

  k_scatter<<<3125, 256, 0, stream>>>(ei, cnt, col);        // also produces degrees in cnt
  k_dinv<<<196, 256, 0, stream>>>(cnt, dinv);

  dim3 blk(256);
  // layer 1 (GEMM output pre-scaled by dinv)
  k_gemm<<<dim3(391, 1), blk, 0, stream>>>(xbf, FD, Wt, FD, hbf, FD, NN, FD, dinv);
  k_agg<<<12500, 256, 0, stream>>>(hbf, dinv, cnt, col, b1, H, 0, hh);
  // layer 2 (input = H[:,0:128))
  k_gemm<<<dim3(391, 1), blk, 0, stream>>>(H, KH, Wt + 16384, FD, hbf, FD, NN, FD, dinv);
  k_agg<<<12500, 256, 0, stream>>>(hbf, dinv, cnt, col, b2, H, 128, hh);
  // layer 3 (input = H[:,128:256))
  k_gemm<<<dim3(391, 1), blk, 0, stream>>>(H + 128, KH, Wt + 32768, FD, hbf, FD, NN, FD, dinv);
  k_agg<<<12500, 256, 0, stream>>>(hbf, dinv, cnt, col, b3, H, 256, hh);

  k_ss<<<256, 64, 0, stream>>>(S, ss);
  // SOM dot GEMM: dots[N][256] = H[N][384] @ Sbf[256][384]^T  (no row scale)
  k_gemm<<<dim3(391, 2), blk, 0, stream>>>(H, KH, Sbf, KH, dots, NU, NN, KH, nullptr);
  k_som<<<391, 256, 0, stream>>>(dots, hh, ss, bat, G);
  k_out<<<64, 64, 0, stream>>>(G, lw, lb, out);
}

// Round 4
// 276.322 us; speedup vs baseline: 1.7021x; 1.1437x over previous
//
#include <hip/hip_runtime.h>

#define NN 50000
#define NE 800000
#define FD 128
#define KH 384
#define NU 256
#define NG 64
#define MAXDEG 64
#define NB 98          // dst buckets of 512 nodes
#define BCAP 10240     // per-bucket capacity (expected 8163 +- ~300)
#define EPB 4096       // edges per k_bin block

typedef __attribute__((__ext_vector_type__(8))) short short8;
typedef __attribute__((__ext_vector_type__(4))) float f32x4;
typedef __attribute__((__ext_vector_type__(2))) float f32x2;

// ---- ws layout (bytes, 16B-aligned) ----
#define OFF_POS   0u           // NB int (+pad)         512     [memset]
#define OFF_G     512u         // 64*256 f32            65536   [memset]
#define OFF_CNT   66048u       // 50048 int             200192
#define OFF_BE    266240u      // NB*BCAP u32           4014080
#define OFF_COL   4280320u     // 50048*64 u16          6406144
#define OFF_DINV  10686464u    // 50048 f32             200192
#define OFF_XBF   10886656u    // NN*128 bf16           12800000
#define OFF_H8    23686656u    // NN*128 fp8            6400000
#define OFF_H     30086656u    // NN*384 bf16           38400000
#define OFF_HH    68486656u    // NN f32                200000
#define OFF_DOTS  68686656u    // NN*256 bf16           25600000
#define OFF_WT    94286656u    // 3*128*128 bf16        98304
#define OFF_SBF   94384960u    // 256*384 bf16          196608
#define OFF_SS    94581568u    // 256 f32               1024   -> total 94582592

__device__ __forceinline__ float b2f(ushort h){
  union { unsigned u; float f; } c; c.u = ((unsigned)h) << 16; return c.f;
}
__device__ __forceinline__ ushort f2b(float f){
  union { float f; unsigned u; } c; c.f = f;
  unsigned u = c.u;
  return (ushort)((u + 0x7fffu + ((u >> 16) & 1u)) >> 16);
}

__global__ void k_convert(const float* __restrict__ s, ushort* __restrict__ d, int n4){
  int i = blockIdx.x * blockDim.x + threadIdx.x;
  if (i >= n4) return;
  float4 v = reinterpret_cast<const float4*>(s)[i];
  ushort4 o; o.x = f2b(v.x); o.y = f2b(v.y); o.z = f2b(v.z); o.w = f2b(v.w);
  reinterpret_cast<ushort4*>(d)[i] = o;
}

// Wt[n][k] = bf16(W[k][n])
__global__ void k_twc(const float* __restrict__ W, ushort* __restrict__ Wt){
  int n = blockIdx.x, k = threadIdx.x;
  Wt[n * FD + k] = f2b(W[k * FD + n]);
}

// phase A: bin edges by dst>>9, dense bucket appends
__global__ __launch_bounds__(256) void k_bin(const int* __restrict__ ei,
                                             int* __restrict__ bucketPos,
                                             unsigned* __restrict__ be){
  __shared__ int hist[NB], base[NB], off[NB];
  int t = threadIdx.x;
  for (int i = t; i < NB; i += 256) hist[i] = 0;
  __syncthreads();
  int e0 = blockIdx.x * EPB;
  int e1 = min(e0 + EPB, NE);
  for (int e = e0 + t; e < e1; e += 256)
    atomicAdd(&hist[ei[NE + e] >> 9], 1);
  __syncthreads();
  for (int i = t; i < NB; i += 256){
    base[i] = atomicAdd(&bucketPos[i], hist[i]);
    off[i] = 0;
  }
  __syncthreads();
  for (int e = e0 + t; e < e1; e += 256){
    int d = ei[NE + e], s = ei[e];
    int b = d >> 9;
    int p = base[b] + atomicAdd(&off[b], 1);
    if (p < BCAP) be[(size_t)b * BCAP + p] = ((unsigned)(d & 511) << 16) | (unsigned)s;
  }
}

// phase B: one block per bucket; LDS degree counters; L2-local col scatter
__global__ __launch_bounds__(256) void k_build(const int* __restrict__ bucketPos,
                                               const unsigned* __restrict__ be,
                                               int* __restrict__ cnt,
                                               ushort* __restrict__ col){
  __shared__ int lcnt[512];
  int t = threadIdx.x, b = blockIdx.x;
  for (int i = t; i < 512; i += 256) lcnt[i] = 0;
  __syncthreads();
  int nE = min(bucketPos[b], BCAP);
  const unsigned* bb = be + (size_t)b * BCAP;
  for (int i = t; i < nE; i += 256){
    unsigned u = bb[i];
    int dl = u >> 16, s = u & 0xffffu;
    int pos = atomicAdd(&lcnt[dl], 1);
    if (pos < MAXDEG) col[(size_t)(b * 512 + dl) * MAXDEG + pos] = (ushort)s;
  }
  __syncthreads();
  for (int i = t; i < 512; i += 256){
    int n = b * 512 + i;
    if (n < NN) cnt[n] = lcnt[i];
  }
}

__global__ void k_dinv(const int* __restrict__ cnt, float* __restrict__ dinv){
  int i = blockIdx.x * blockDim.x + threadIdx.x;
  if (i < NN) dinv[i] = rsqrtf((float)(cnt[i] + 1));
}

// C[M][Nt] = A[M][K] * B_T[Nt][K]^T (bf16 in, fp32 acc)
// epilogue: optional row scale rs; output bf16 (outFp8=0) or fp8 e4m3 (outFp8=1)
__global__ __launch_bounds__(256) void k_gemm(
    const ushort* __restrict__ A, int lda,
    const ushort* __restrict__ B, int ldb,
    void* __restrict__ Cv, int ldc, int M, int K,
    const float* __restrict__ rs, int outFp8){
  __shared__ __align__(16) ushort Al[128 * 64];
  __shared__ __align__(16) ushort Bl[128 * 64];
  const int t = threadIdx.x;
  const int lane = t & 63, w = t >> 6;
  const int wr = w >> 1, wc = w & 1;
  const int ln = lane & 15, hi = lane >> 4;
  const int mBase = blockIdx.x * 128, nBase = blockIdx.y * 128;

  f32x4 zero = {0.f, 0.f, 0.f, 0.f};
  f32x4 acc[4][4];
  #pragma unroll
  for (int i = 0; i < 4; ++i)
    #pragma unroll
    for (int j = 0; j < 4; ++j) acc[i][j] = zero;

  for (int kb = 0; kb < K; kb += 64){
    __syncthreads();
    #pragma unroll
    for (int it = 0; it < 4; ++it){
      int idx = t + it * 256;
      int row = idx >> 3, seg = idx & 7;
      int off = (row * 128 + seg * 16) ^ ((row & 7) << 4);
      uint4 va = make_uint4(0u, 0u, 0u, 0u);
      int gm = mBase + row;
      if (gm < M) va = *reinterpret_cast<const uint4*>(A + (size_t)gm * lda + kb + seg * 8);
      *reinterpret_cast<uint4*>(reinterpret_cast<char*>(Al) + off) = va;
      int gn = nBase + row;
      uint4 vb = *reinterpret_cast<const uint4*>(B + (size_t)gn * ldb + kb + seg * 8);
      *reinterpret_cast<uint4*>(reinterpret_cast<char*>(Bl) + off) = vb;
    }
    __syncthreads();
    #pragma unroll
    for (int ks = 0; ks < 2; ++ks){
      short8 a[4], b[4];
      #pragma unroll
      for (int f = 0; f < 4; ++f){
        int ra = wr * 64 + f * 16 + ln;
        int oa = (ra * 128 + ks * 64 + hi * 16) ^ ((ra & 7) << 4);
        a[f] = *reinterpret_cast<const short8*>(reinterpret_cast<const char*>(Al) + oa);
        int rb = wc * 64 + f * 16 + ln;
        int ob = (rb * 128 + ks * 64 + hi * 16) ^ ((rb & 7) << 4);
        b[f] = *reinterpret_cast<const short8*>(reinterpret_cast<const char*>(Bl) + ob);
      }
      #pragma unroll
      for (int fm = 0; fm < 4; ++fm)
        #pragma unroll
        for (int fn = 0; fn < 4; ++fn)
          acc[fm][fn] = __builtin_amdgcn_mfma_f32_16x16x32_bf16(a[fm], b[fn], acc[fm][fn], 0, 0, 0);
    }
  }
  #pragma unroll
  for (int fm = 0; fm < 4; ++fm){
    int r0 = mBase + wr * 64 + fm * 16 + hi * 4;
    float rsv[4] = {1.f, 1.f, 1.f, 1.f};
    if (rs){
      #pragma unroll
      for (int j = 0; j < 4; ++j) if (r0 + j < M) rsv[j] = rs[r0 + j];
    }
    #pragma unroll
    for (int fn = 0; fn < 4; ++fn){
      int cg = nBase + wc * 64 + fn * 16 + ln;
      f32x4 v = acc[fm][fn];
      if (outFp8){
        unsigned char* C8 = (unsigned char*)Cv;
        int p01 = __builtin_amdgcn_cvt_pk_fp8_f32(v[0] * rsv[0], v[1] * rsv[1], 0, false);
        int p23 = __builtin_amdgcn_cvt_pk_fp8_f32(v[2] * rsv[2], v[3] * rsv[3], 0, false);
        if (r0     < M) C8[(size_t)(r0    ) * ldc + cg] = (unsigned char)(p01);
        if (r0 + 1 < M) C8[(size_t)(r0 + 1) * ldc + cg] = (unsigned char)(p01 >> 8);
        if (r0 + 2 < M) C8[(size_t)(r0 + 2) * ldc + cg] = (unsigned char)(p23);
        if (r0 + 3 < M) C8[(size_t)(r0 + 3) * ldc + cg] = (unsigned char)(p23 >> 8);
      } else {
        ushort* C = (ushort*)Cv;
        #pragma unroll
        for (int j = 0; j < 4; ++j){
          int rg = r0 + j;
          if (rg < M) C[(size_t)rg * ldc + cg] = f2b(v[j] * rsv[j]);
        }
      }
    }
  }
}

// wave per node, 4 groups x 16 lanes; lane owns 8 features (8B fp8 rows).
// input hs8 is fp8, PRE-SCALED by dinv:
//   out[n] = lrelu( dinv[n] * (hs[n] + sum_j hs[col[j]]) + bias )
__global__ __launch_bounds__(256) void k_agg(
    const unsigned char* __restrict__ hs8, const float* __restrict__ dinv,
    const int* __restrict__ cnt, const ushort* __restrict__ col,
    const float* __restrict__ bias, ushort* __restrict__ H, int cOff,
    float* __restrict__ hh){
  int lane = threadIdx.x & 63;
  int n = blockIdx.x * 4 + (threadIdx.x >> 6);
  if (n >= NN) return;
  const int g = lane >> 4, ln = lane & 15;
  const int f0 = ln * 8;
  float acc[8] = {0.f,0.f,0.f,0.f,0.f,0.f,0.f,0.f};
  if (g == 0){                     // self loop
    uint2 sv = *reinterpret_cast<const uint2*>(hs8 + (size_t)n * FD + f0);
    f32x2 e;
    e = __builtin_amdgcn_cvt_pk_f32_fp8((int)sv.x, false); acc[0] = e.x; acc[1] = e.y;
    e = __builtin_amdgcn_cvt_pk_f32_fp8((int)sv.x, true ); acc[2] = e.x; acc[3] = e.y;
    e = __builtin_amdgcn_cvt_pk_f32_fp8((int)sv.y, false); acc[4] = e.x; acc[5] = e.y;
    e = __builtin_amdgcn_cvt_pk_f32_fp8((int)sv.y, true ); acc[6] = e.x; acc[7] = e.y;
  }
  int ne = cnt[n]; if (ne > MAXDEG) ne = MAXDEG;
  const ushort* cl = col + (size_t)n * MAXDEG;
  for (int j = 0; j < ne; j += 16){
    int i0 = j + g, i1 = j + 4 + g, i2 = j + 8 + g, i3 = j + 12 + g;
    int s0 = n, s1 = n, s2 = n, s3 = n;
    float w0 = 0.f, w1 = 0.f, w2 = 0.f, w3 = 0.f;
    if (i0 < ne){ s0 = cl[i0]; w0 = 1.f; }
    if (i1 < ne){ s1 = cl[i1]; w1 = 1.f; }
    if (i2 < ne){ s2 = cl[i2]; w2 = 1.f; }
    if (i3 < ne){ s3 = cl[i3]; w3 = 1.f; }
    uint2 r0v = *reinterpret_cast<const uint2*>(hs8 + (size_t)s0 * FD + f0);
    uint2 r1v = *reinterpret_cast<const uint2*>(hs8 + (size_t)s1 * FD + f0);
    uint2 r2v = *reinterpret_cast<const uint2*>(hs8 + (size_t)s2 * FD + f0);
    uint2 r3v = *reinterpret_cast<const uint2*>(hs8 + (size_t)s3 * FD + f0);
    f32x2 e;
    e = __builtin_amdgcn_cvt_pk_f32_fp8((int)r0v.x, false); acc[0] += e.x*w0; acc[1] += e.y*w0;
    e = __builtin_amdgcn_cvt_pk_f32_fp8((int)r0v.x, true ); acc[2] += e.x*w0; acc[3] += e.y*w0;
    e = __builtin_amdgcn_cvt_pk_f32_fp8((int)r0v.y, false); acc[4] += e.x*w0; acc[5] += e.y*w0;
    e = __builtin_amdgcn_cvt_pk_f32_fp8((int)r0v.y, true ); acc[6] += e.x*w0; acc[7] += e.y*w0;
    e = __builtin_amdgcn_cvt_pk_f32_fp8((int)r1v.x, false); acc[0] += e.x*w1; acc[1] += e.y*w1;
    e = __builtin_amdgcn_cvt_pk_f32_fp8((int)r1v.x, true ); acc[2] += e.x*w1; acc[3] += e.y*w1;
    e = __builtin_amdgcn_cvt_pk_f32_fp8((int)r1v.y, false); acc[4] += e.x*w1; acc[5] += e.y*w1;
    e = __builtin_amdgcn_cvt_pk_f32_fp8((int)r1v.y, true ); acc[6] += e.x*w1; acc[7] += e.y*w1;
    e = __builtin_amdgcn_cvt_pk_f32_fp8((int)r2v.x, false); acc[0] += e.x*w2; acc[1] += e.y*w2;
    e = __builtin_amdgcn_cvt_pk_f32_fp8((int)r2v.x, true ); acc[2] += e.x*w2; acc[3] += e.y*w2;
    e = __builtin_amdgcn_cvt_pk_f32_fp8((int)r2v.y, false); acc[4] += e.x*w2; acc[5] += e.y*w2;
    e = __builtin_amdgcn_cvt_pk_f32_fp8((int)r2v.y, true ); acc[6] += e.x*w2; acc[7] += e.y*w2;
    e = __builtin_amdgcn_cvt_pk_f32_fp8((int)r3v.x, false); acc[0] += e.x*w3; acc[1] += e.y*w3;
    e = __builtin_amdgcn_cvt_pk_f32_fp8((int)r3v.x, true ); acc[2] += e.x*w3; acc[3] += e.y*w3;
    e = __builtin_amdgcn_cvt_pk_f32_fp8((int)r3v.y, false); acc[4] += e.x*w3; acc[5] += e.y*w3;
    e = __builtin_amdgcn_cvt_pk_f32_fp8((int)r3v.y, true ); acc[6] += e.x*w3; acc[7] += e.y*w3;
  }
  #pragma unroll
  for (int k = 0; k < 8; ++k){
    acc[k] += __shfl_xor(acc[k], 16);
    acc[k] += __shfl_xor(acc[k], 32);
  }
  float di = dinv[n];
  float ssq = 0.f;
  short8 o;
  #pragma unroll
  for (int k = 0; k < 8; ++k){
    float v = acc[k] * di + bias[f0 + k];
    v = v > 0.f ? v : 0.01f * v;
    ssq += v * v;
    o[k] = (short)f2b(v);
  }
  if (g == 0){
    *reinterpret_cast<short8*>(H + (size_t)n * KH + cOff + f0) = o;
    #pragma unroll
    for (int m = 1; m < 16; m <<= 1) ssq += __shfl_xor(ssq, m);
    if (ln == 0){
      if (cOff == 0) hh[n] = ssq;
      else           hh[n] += ssq;
    }
  }
}

__global__ void k_ss(const float* __restrict__ S, float* __restrict__ ss){
  int u = blockIdx.x, lane = threadIdx.x;
  const float* p = S + (size_t)u * KH + lane * 6;
  float s = 0.f;
  #pragma unroll
  for (int j = 0; j < 6; ++j){ float v = p[j]; s += v * v; }
  #pragma unroll
  for (int o = 32; o; o >>= 1) s += __shfl_down(s, o);
  if (lane == 0) ss[u] = s;
}

__global__ __launch_bounds__(256) void k_som(
    const ushort* __restrict__ dots, const float* __restrict__ hh,
    const float* __restrict__ ss, const int* __restrict__ batch,
    float* __restrict__ G){
  int lane = threadIdx.x & 63;
  int gw = blockIdx.x * 4 + (threadIdx.x >> 6);
  int n0 = gw * 32;
  if (n0 >= NN) return;
  int n1 = min(n0 + 32, NN);
  float ssr[4];
  #pragma unroll
  for (int j = 0; j < 4; ++j) ssr[j] = ss[lane * 4 + j];
  float g[4] = {0.f, 0.f, 0.f, 0.f};
  int curb = batch[n0];
  for (int n = n0; n < n1; ++n){
    int b = batch[n];
    if (b != curb){
      #pragma unroll
      for (int j = 0; j < 4; ++j){ atomicAdd(&G[curb * NU + lane * 4 + j], g[j]); g[j] = 0.f; }
      curb = b;
    }
    ushort4 dv = *reinterpret_cast<const ushort4*>(dots + (size_t)n * NU + lane * 4);
    float v0 = ssr[0] - 2.f * b2f(dv.x);
    float v1 = ssr[1] - 2.f * b2f(dv.y);
    float v2 = ssr[2] - 2.f * b2f(dv.z);
    float v3 = ssr[3] - 2.f * b2f(dv.w);
    float mv = v0; int mi = lane * 4;
    if (v1 < mv){ mv = v1; mi = lane * 4 + 1; }
    if (v2 < mv){ mv = v2; mi = lane * 4 + 2; }
    if (v3 < mv){ mv = v3; mi = lane * 4 + 3; }
    #pragma unroll
    for (int o = 1; o < 64; o <<= 1){
      float ov = __shfl_xor(mv, o);
      int   oi = __shfl_xor(mi, o);
      if (ov < mv || (ov == mv && oi < mi)){ mv = ov; mi = oi; }
    }
    float d2 = fmaxf(hh[n] + mv, 0.f);
    float hsv = __expf(-sqrtf(d2));
    int wi = mi >> 4, wj = mi & 15;
    #pragma unroll
    for (int j = 0; j < 4; ++j){
      int c = lane * 4 + j;
      float dx = (float)((c >> 4) - wi), dy = (float)((c & 15) - wj);
      g[j] += hsv * __expf(-(dx * dx + dy * dy) * 0.125f);
    }
  }
  #pragma unroll
  for (int j = 0; j < 4; ++j) atomicAdd(&G[curb * NU + lane * 4 + j], g[j]);
}

__global__ void k_out(const float* __restrict__ G, const float* __restrict__ lw,
                      const float* __restrict__ lb, float* __restrict__ out){
  int b = blockIdx.x, lane = threadIdx.x;
  float s = 0.f;
  #pragma unroll
  for (int j = 0; j < 4; ++j) s += G[b * NU + lane * 4 + j] * lw[lane * 4 + j];
  #pragma unroll
  for (int o = 32; o; o >>= 1) s += __shfl_down(s, o);
  if (lane == 0) out[b] = 1.f / (1.f + __expf(-(s + lb[0])));
}

extern "C" void kernel_launch(void* const* d_in, const int* in_sizes, int n_in,
                              void* d_out, int out_size, void* d_ws, size_t ws_size,
                              hipStream_t stream){
  const float* x   = (const float*)d_in[0];
  const int*   ei  = (const int*)d_in[1];
  const int*   bat = (const int*)d_in[2];
  const float* W1  = (const float*)d_in[3];
  const float* b1  = (const float*)d_in[4];
  const float* W2  = (const float*)d_in[5];
  const float* b2  = (const float*)d_in[6];
  const float* W3  = (const float*)d_in[7];
  const float* b3  = (const float*)d_in[8];
  const float* S   = (const float*)d_in[9];
  const float* lw  = (const float*)d_in[10];
  const float* lb  = (const float*)d_in[11];
  float* out = (float*)d_out;
  char* w = (char*)d_ws;

  int*      pos  = (int*)     (w + OFF_POS);
  float*    G    = (float*)   (w + OFF_G);
  int*      cnt  = (int*)     (w + OFF_CNT);
  unsigned* be   = (unsigned*)(w + OFF_BE);
  ushort*   col  = (ushort*)  (w + OFF_COL);
  float*    dinv = (float*)   (w + OFF_DINV);
  ushort*   xbf  = (ushort*)  (w + OFF_XBF);
  unsigned char* h8 = (unsigned char*)(w + OFF_H8);
  ushort*   H    = (ushort*)  (w + OFF_H);
  float*    hh   = (float*)   (w + OFF_HH);
  ushort*   dots = (ushort*)  (w + OFF_DOTS);
  ushort*   Wt   = (ushort*)  (w + OFF_WT);
  ushort*   Sbf  = (ushort*)  (w + OFF_SBF);
  float*    ss   = (float*)   (w + OFF_SS);

  hipMemsetAsync(w, 0, 66048, stream);                      // pos + G

  k_convert<<<6250, 256, 0, stream>>>(x, xbf, 1600000);
  k_convert<<<96,   256, 0, stream>>>(S, Sbf, 24576);
  k_twc<<<128, 128, 0, stream>>>(W1, Wt);
  k_twc<<<128, 128, 0, stream>>>(W2, Wt + 16384);
  k_twc<<<128, 128, 0, stream>>>(W3, Wt + 32768);

  k_bin<<<196, 256, 0, stream>>>(ei, pos, be);
  k_build<<<NB, 256, 0, stream>>>(pos, be, cnt, col);
  k_dinv<<<196, 256, 0, stream>>>(cnt, dinv);

  dim3 blk(256);
  // layer 1: GEMM -> fp8 row-scaled table
  k_gemm<<<dim3(391, 1), blk, 0, stream>>>(xbf, FD, Wt, FD, h8, FD, NN, FD, dinv, 1);
  k_agg<<<12500, 256, 0, stream>>>(h8, dinv, cnt, col, b1, H, 0, hh);
  // layer 2
  k_gemm<<<dim3(391, 1), blk, 0, stream>>>(H, KH, Wt + 16384, FD, h8, FD, NN, FD, dinv, 1);
  k_agg<<<12500, 256, 0, stream>>>(h8, dinv, cnt, col, b2, H, 128, hh);
  // layer 3
  k_gemm<<<dim3(391, 1), blk, 0, stream>>>(H + 128, KH, Wt + 32768, FD, h8, FD, NN, FD, dinv, 1);
  k_agg<<<12500, 256, 0, stream>>>(h8, dinv, cnt, col, b3, H, 256, hh);

  k_ss<<<256, 64, 0, stream>>>(S, ss);
  // SOM dot GEMM: dots[N][256] = H[N][384] @ Sbf[256][384]^T (bf16 out)
  k_gemm<<<dim3(391, 2), blk, 0, stream>>>(H, KH, Sbf, KH, dots, NU, NN, KH, nullptr, 0);
  k_som<<<391, 256, 0, stream>>>(dots, hh, ss, bat, G);
  k_out<<<64, 64, 0, stream>>>(G, lw, lb, out);
}

// Round 5
// 242.668 us; speedup vs baseline: 1.9382x; 1.1387x over previous
//
#include <hip/hip_runtime.h>

#define NN 50000
#define NE 800000
#define FD 128
#define KH 384
#define NU 256
#define NG 64
#define MAXDEG 64
#define NB 98          // dst buckets of 512 nodes
#define BCAP 10240     // per-bucket capacity (expected 8163 +- ~300)
#define EPB 4096       // edges per k_bin block

typedef __attribute__((__ext_vector_type__(8))) short short8;
typedef __attribute__((__ext_vector_type__(4))) float f32x4;
typedef __attribute__((__ext_vector_type__(2))) float f32x2;

// ---- ws layout (bytes, 16B-aligned) ----
#define OFF_POS   0u           // NB int (+pad)         512     [memset]
#define OFF_G     512u         // 64*256 f32            65536   [memset]
#define OFF_CNT   66048u       // 50048 int             200192
#define OFF_BE    266240u      // NB*BCAP u32           4014080
#define OFF_COL   4280320u     // 50048*64 u16          6406144
#define OFF_DINV  10686464u    // 50048 f32             200192
#define OFF_XBF   10886656u    // NN*128 bf16           12800000
#define OFF_H8    23686656u    // NN*128 fp8            6400000
#define OFF_H     30086656u    // NN*384 bf16           38400000
#define OFF_HH    68486656u    // NN f32                200000
#define OFF_WT    68686656u    // 3*128*128 bf16        98304
#define OFF_SBF   68784960u    // 256*384 bf16          196608
#define OFF_SS    68981568u    // 256 f32               1024   -> total 68982592

__device__ __forceinline__ float b2f(ushort h){
  union { unsigned u; float f; } c; c.u = ((unsigned)h) << 16; return c.f;
}
__device__ __forceinline__ ushort f2b(float f){
  union { float f; unsigned u; } c; c.f = f;
  unsigned u = c.u;
  return (ushort)((u + 0x7fffu + ((u >> 16) & 1u)) >> 16);
}

__global__ void k_convert(const float* __restrict__ s, ushort* __restrict__ d, int n4){
  int i = blockIdx.x * blockDim.x + threadIdx.x;
  if (i >= n4) return;
  float4 v = reinterpret_cast<const float4*>(s)[i];
  ushort4 o; o.x = f2b(v.x); o.y = f2b(v.y); o.z = f2b(v.z); o.w = f2b(v.w);
  reinterpret_cast<ushort4*>(d)[i] = o;
}

// Wt[n][k] = bf16(W[k][n])
__global__ void k_twc(const float* __restrict__ W, ushort* __restrict__ Wt){
  int n = blockIdx.x, k = threadIdx.x;
  Wt[n * FD + k] = f2b(W[k * FD + n]);
}

// phase A: bin edges by dst>>9, dense bucket appends
__global__ __launch_bounds__(256) void k_bin(const int* __restrict__ ei,
                                             int* __restrict__ bucketPos,
                                             unsigned* __restrict__ be){
  __shared__ int hist[NB], base[NB], off[NB];
  int t = threadIdx.x;
  for (int i = t; i < NB; i += 256) hist[i] = 0;
  __syncthreads();
  int e0 = blockIdx.x * EPB;
  int e1 = min(e0 + EPB, NE);
  for (int e = e0 + t; e < e1; e += 256)
    atomicAdd(&hist[ei[NE + e] >> 9], 1);
  __syncthreads();
  for (int i = t; i < NB; i += 256){
    base[i] = atomicAdd(&bucketPos[i], hist[i]);
    off[i] = 0;
  }
  __syncthreads();
  for (int e = e0 + t; e < e1; e += 256){
    int d = ei[NE + e], s = ei[e];
    int b = d >> 9;
    int p = base[b] + atomicAdd(&off[b], 1);
    if (p < BCAP) be[(size_t)b * BCAP + p] = ((unsigned)(d & 511) << 16) | (unsigned)s;
  }
}

// phase B: one block per bucket; LDS degree counters; L2-local col scatter
__global__ __launch_bounds__(256) void k_build(const int* __restrict__ bucketPos,
                                               const unsigned* __restrict__ be,
                                               int* __restrict__ cnt,
                                               ushort* __restrict__ col){
  __shared__ int lcnt[512];
  int t = threadIdx.x, b = blockIdx.x;
  for (int i = t; i < 512; i += 256) lcnt[i] = 0;
  __syncthreads();
  int nE = min(bucketPos[b], BCAP);
  const unsigned* bb = be + (size_t)b * BCAP;
  for (int i = t; i < nE; i += 256){
    unsigned u = bb[i];
    int dl = u >> 16, s = u & 0xffffu;
    int pos = atomicAdd(&lcnt[dl], 1);
    if (pos < MAXDEG) col[(size_t)(b * 512 + dl) * MAXDEG + pos] = (ushort)s;
  }
  __syncthreads();
  for (int i = t; i < 512; i += 256){
    int n = b * 512 + i;
    if (n < NN) cnt[n] = lcnt[i];
  }
}

__global__ void k_dinv(const int* __restrict__ cnt, float* __restrict__ dinv){
  int i = blockIdx.x * blockDim.x + threadIdx.x;
  if (i < NN) dinv[i] = rsqrtf((float)(cnt[i] + 1));
}

// C[M][Nt] = A[M][K] * B_T[Nt][K]^T (bf16 in, fp32 acc)
// epilogue: optional row scale rs; output bf16 (outFp8=0) or fp8 e4m3 (outFp8=1)
__global__ __launch_bounds__(256) void k_gemm(
    const ushort* __restrict__ A, int lda,
    const ushort* __restrict__ B, int ldb,
    void* __restrict__ Cv, int ldc, int M, int K,
    const float* __restrict__ rs, int outFp8){
  __shared__ __align__(16) ushort Al[128 * 64];
  __shared__ __align__(16) ushort Bl[128 * 64];
  const int t = threadIdx.x;
  const int lane = t & 63, w = t >> 6;
  const int wr = w >> 1, wc = w & 1;
  const int ln = lane & 15, hi = lane >> 4;
  const int mBase = blockIdx.x * 128, nBase = blockIdx.y * 128;

  f32x4 zero = {0.f, 0.f, 0.f, 0.f};
  f32x4 acc[4][4];
  #pragma unroll
  for (int i = 0; i < 4; ++i)
    #pragma unroll
    for (int j = 0; j < 4; ++j) acc[i][j] = zero;

  for (int kb = 0; kb < K; kb += 64){
    __syncthreads();
    #pragma unroll
    for (int it = 0; it < 4; ++it){
      int idx = t + it * 256;
      int row = idx >> 3, seg = idx & 7;
      int off = (row * 128 + seg * 16) ^ ((row & 7) << 4);
      uint4 va = make_uint4(0u, 0u, 0u, 0u);
      int gm = mBase + row;
      if (gm < M) va = *reinterpret_cast<const uint4*>(A + (size_t)gm * lda + kb + seg * 8);
      *reinterpret_cast<uint4*>(reinterpret_cast<char*>(Al) + off) = va;
      int gn = nBase + row;
      uint4 vb = *reinterpret_cast<const uint4*>(B + (size_t)gn * ldb + kb + seg * 8);
      *reinterpret_cast<uint4*>(reinterpret_cast<char*>(Bl) + off) = vb;
    }
    __syncthreads();
    #pragma unroll
    for (int ks = 0; ks < 2; ++ks){
      short8 a[4], b[4];
      #pragma unroll
      for (int f = 0; f < 4; ++f){
        int ra = wr * 64 + f * 16 + ln;
        int oa = (ra * 128 + ks * 64 + hi * 16) ^ ((ra & 7) << 4);
        a[f] = *reinterpret_cast<const short8*>(reinterpret_cast<const char*>(Al) + oa);
        int rb = wc * 64 + f * 16 + ln;
        int ob = (rb * 128 + ks * 64 + hi * 16) ^ ((rb & 7) << 4);
        b[f] = *reinterpret_cast<const short8*>(reinterpret_cast<const char*>(Bl) + ob);
      }
      #pragma unroll
      for (int fm = 0; fm < 4; ++fm)
        #pragma unroll
        for (int fn = 0; fn < 4; ++fn)
          acc[fm][fn] = __builtin_amdgcn_mfma_f32_16x16x32_bf16(a[fm], b[fn], acc[fm][fn], 0, 0, 0);
    }
  }
  #pragma unroll
  for (int fm = 0; fm < 4; ++fm){
    int r0 = mBase + wr * 64 + fm * 16 + hi * 4;
    float rsv[4] = {1.f, 1.f, 1.f, 1.f};
    if (rs){
      #pragma unroll
      for (int j = 0; j < 4; ++j) if (r0 + j < M) rsv[j] = rs[r0 + j];
    }
    #pragma unroll
    for (int fn = 0; fn < 4; ++fn){
      int cg = nBase + wc * 64 + fn * 16 + ln;
      f32x4 v = acc[fm][fn];
      if (outFp8){
        unsigned char* C8 = (unsigned char*)Cv;
        int p01 = __builtin_amdgcn_cvt_pk_fp8_f32(v[0] * rsv[0], v[1] * rsv[1], 0, false);
        int p23 = __builtin_amdgcn_cvt_pk_fp8_f32(v[2] * rsv[2], v[3] * rsv[3], 0, false);
        if (r0     < M) C8[(size_t)(r0    ) * ldc + cg] = (unsigned char)(p01);
        if (r0 + 1 < M) C8[(size_t)(r0 + 1) * ldc + cg] = (unsigned char)(p01 >> 8);
        if (r0 + 2 < M) C8[(size_t)(r0 + 2) * ldc + cg] = (unsigned char)(p23);
        if (r0 + 3 < M) C8[(size_t)(r0 + 3) * ldc + cg] = (unsigned char)(p23 >> 8);
      } else {
        ushort* C = (ushort*)Cv;
        #pragma unroll
        for (int j = 0; j < 4; ++j){
          int rg = r0 + j;
          if (rg < M) C[(size_t)rg * ldc + cg] = f2b(v[j] * rsv[j]);
        }
      }
    }
  }
}

// Fused SOM GEMM + argmin + gaussian scatter.
// 512 threads, 8 waves (2 x 4), tile 128 rows x 256 units, K = 384.
__global__ __launch_bounds__(512) void k_gsom(
    const ushort* __restrict__ A /* H, lda = KH */,
    const ushort* __restrict__ B /* Sbf [256][384] */,
    const float* __restrict__ ss, const float* __restrict__ hh,
    const int* __restrict__ batch, float* __restrict__ G, int M){
  __shared__ __align__(16) ushort Al[128 * 64];   // 16 KB
  __shared__ __align__(16) ushort Bl[256 * 64];   // 32 KB
  __shared__ float l_ss[NU];
  __shared__ float redv[4][128];
  __shared__ int   redi[4][128];
  __shared__ float l_hs[128];
  __shared__ int   l_win[128];
  __shared__ int   l_bat[128];

  const int t = threadIdx.x;
  const int lane = t & 63, w = t >> 6;
  const int wr = w >> 2, wc = w & 3;              // 2 x 4 wave grid
  const int ln = lane & 15, hi = lane >> 4;
  const int mBase = blockIdx.x * 128;

  if (t < NU) l_ss[t] = ss[t];

  f32x4 zero = {0.f, 0.f, 0.f, 0.f};
  f32x4 acc[4][4];
  #pragma unroll
  for (int i = 0; i < 4; ++i)
    #pragma unroll
    for (int j = 0; j < 4; ++j) acc[i][j] = zero;

  for (int kb = 0; kb < KH; kb += 64){
    __syncthreads();
    #pragma unroll
    for (int it = 0; it < 2; ++it){               // A: 1024 uint4
      int idx = t + it * 512;
      int row = idx >> 3, seg = idx & 7;
      int off = (row * 128 + seg * 16) ^ ((row & 7) << 4);
      uint4 va = make_uint4(0u, 0u, 0u, 0u);
      int gm = mBase + row;
      if (gm < M) va = *reinterpret_cast<const uint4*>(A + (size_t)gm * KH + kb + seg * 8);
      *reinterpret_cast<uint4*>(reinterpret_cast<char*>(Al) + off) = va;
    }
    #pragma unroll
    for (int it = 0; it < 4; ++it){               // B: 2048 uint4
      int idx = t + it * 512;
      int row = idx >> 3, seg = idx & 7;
      int off = (row * 128 + seg * 16) ^ ((row & 7) << 4);
      uint4 vb = *reinterpret_cast<const uint4*>(B + (size_t)row * KH + kb + seg * 8);
      *reinterpret_cast<uint4*>(reinterpret_cast<char*>(Bl) + off) = vb;
    }
    __syncthreads();
    #pragma unroll
    for (int ks = 0; ks < 2; ++ks){
      short8 a[4], b[4];
      #pragma unroll
      for (int f = 0; f < 4; ++f){
        int ra = wr * 64 + f * 16 + ln;
        int oa = (ra * 128 + ks * 64 + hi * 16) ^ ((ra & 7) << 4);
        a[f] = *reinterpret_cast<const short8*>(reinterpret_cast<const char*>(Al) + oa);
        int rb = wc * 64 + f * 16 + ln;
        int ob = (rb * 128 + ks * 64 + hi * 16) ^ ((rb & 7) << 4);
        b[f] = *reinterpret_cast<const short8*>(reinterpret_cast<const char*>(Bl) + ob);
      }
      #pragma unroll
      for (int fm = 0; fm < 4; ++fm)
        #pragma unroll
        for (int fn = 0; fn < 4; ++fn)
          acc[fm][fn] = __builtin_amdgcn_mfma_f32_16x16x32_bf16(a[fm], b[fn], acc[fm][fn], 0, 0, 0);
    }
  }

  // ---- per-wave argmin over its 64 units, per row ----
  #pragma unroll
  for (int fm = 0; fm < 4; ++fm){
    #pragma unroll
    for (int j = 0; j < 4; ++j){
      float mv = 3.4e38f; int mi = 0;
      #pragma unroll
      for (int fn = 0; fn < 4; ++fn){
        int c = wc * 64 + fn * 16 + ln;
        float v = l_ss[c] - 2.f * acc[fm][fn][j];
        if (v < mv || (v == mv && c < mi)){ mv = v; mi = c; }
      }
      #pragma unroll
      for (int m = 1; m < 16; m <<= 1){
        float ov = __shfl_xor(mv, m);
        int   oi = __shfl_xor(mi, m);
        if (ov < mv || (ov == mv && oi < mi)){ mv = ov; mi = oi; }
      }
      if (ln == 0){
        int row = wr * 64 + fm * 16 + hi * 4 + j;
        redv[wc][row] = mv; redi[wc][row] = mi;
      }
    }
  }
  __syncthreads();

  // ---- combine 4 wc-waves, finish hs per row ----
  if (t < 128){
    int r = mBase + t;
    float mv = redv[0][t]; int mi = redi[0][t];
    #pragma unroll
    for (int q = 1; q < 4; ++q){
      float ov = redv[q][t]; int oi = redi[q][t];
      if (ov < mv || (ov == mv && oi < mi)){ mv = ov; mi = oi; }
    }
    if (r < M){
      float d2 = fmaxf(hh[r] + mv, 0.f);
      l_hs[t] = __expf(-sqrtf(d2));
      l_win[t] = mi;
      l_bat[t] = batch[r];
    } else {
      l_hs[t] = 0.f; l_win[t] = 0; l_bat[t] = -1;
    }
  }
  __syncthreads();

  // ---- gaussian accumulation: wave w handles rows [w*16, w*16+16) ----
  {
    float g0 = 0.f, g1 = 0.f, g2 = 0.f, g3 = 0.f;
    int curb = -1;
    int c0 = lane * 4;
    float cx = (float)(c0 >> 4);
    #pragma unroll
    for (int rr = 0; rr < 16; ++rr){
      int row = w * 16 + rr;
      int b = l_bat[row];
      if (b < 0) continue;
      if (b != curb){
        if (curb >= 0){
          atomicAdd(&G[curb * NU + c0    ], g0);
          atomicAdd(&G[curb * NU + c0 + 1], g1);
          atomicAdd(&G[curb * NU + c0 + 2], g2);
          atomicAdd(&G[curb * NU + c0 + 3], g3);
          g0 = g1 = g2 = g3 = 0.f;
        }
        curb = b;
      }
      float hs = l_hs[row];
      int win = l_win[row];
      float wi = (float)(win >> 4), wj = (float)(win & 15);
      float dx = cx - wi;
      float ex = hs * __expf(-dx * dx * 0.125f);
      float dy0 = (float)((c0    ) & 15) - wj;
      float dy1 = (float)((c0 + 1) & 15) - wj;
      float dy2 = (float)((c0 + 2) & 15) - wj;
      float dy3 = (float)((c0 + 3) & 15) - wj;
      g0 += ex * __expf(-dy0 * dy0 * 0.125f);
      g1 += ex * __expf(-dy1 * dy1 * 0.125f);
      g2 += ex * __expf(-dy2 * dy2 * 0.125f);
      g3 += ex * __expf(-dy3 * dy3 * 0.125f);
    }
    if (curb >= 0){
      atomicAdd(&G[curb * NU + c0    ], g0);
      atomicAdd(&G[curb * NU + c0 + 1], g1);
      atomicAdd(&G[curb * NU + c0 + 2], g2);
      atomicAdd(&G[curb * NU + c0 + 3], g3);
    }
  }
}

// wave per node, 4 groups x 16 lanes; lane owns 8 features (8B fp8 rows).
__global__ __launch_bounds__(256) void k_agg(
    const unsigned char* __restrict__ hs8, const float* __restrict__ dinv,
    const int* __restrict__ cnt, const ushort* __restrict__ col,
    const float* __restrict__ bias, ushort* __restrict__ H, int cOff,
    float* __restrict__ hh){
  int lane = threadIdx.x & 63;
  int n = blockIdx.x * 4 + (threadIdx.x >> 6);
  if (n >= NN) return;
  const int g = lane >> 4, ln = lane & 15;
  const int f0 = ln * 8;
  float acc[8] = {0.f,0.f,0.f,0.f,0.f,0.f,0.f,0.f};
  if (g == 0){                     // self loop
    uint2 sv = *reinterpret_cast<const uint2*>(hs8 + (size_t)n * FD + f0);
    f32x2 e;
    e = __builtin_amdgcn_cvt_pk_f32_fp8((int)sv.x, false); acc[0] = e.x; acc[1] = e.y;
    e = __builtin_amdgcn_cvt_pk_f32_fp8((int)sv.x, true ); acc[2] = e.x; acc[3] = e.y;
    e = __builtin_amdgcn_cvt_pk_f32_fp8((int)sv.y, false); acc[4] = e.x; acc[5] = e.y;
    e = __builtin_amdgcn_cvt_pk_f32_fp8((int)sv.y, true ); acc[6] = e.x; acc[7] = e.y;
  }
  int ne = cnt[n]; if (ne > MAXDEG) ne = MAXDEG;
  const ushort* cl = col + (size_t)n * MAXDEG;
  for (int j = 0; j < ne; j += 16){
    int i0 = j + g, i1 = j + 4 + g, i2 = j + 8 + g, i3 = j + 12 + g;
    int s0 = n, s1 = n, s2 = n, s3 = n;
    float w0 = 0.f, w1 = 0.f, w2 = 0.f, w3 = 0.f;
    if (i0 < ne){ s0 = cl[i0]; w0 = 1.f; }
    if (i1 < ne){ s1 = cl[i1]; w1 = 1.f; }
    if (i2 < ne){ s2 = cl[i2]; w2 = 1.f; }
    if (i3 < ne){ s3 = cl[i3]; w3 = 1.f; }
    uint2 r0v = *reinterpret_cast<const uint2*>(hs8 + (size_t)s0 * FD + f0);
    uint2 r1v = *reinterpret_cast<const uint2*>(hs8 + (size_t)s1 * FD + f0);
    uint2 r2v = *reinterpret_cast<const uint2*>(hs8 + (size_t)s2 * FD + f0);
    uint2 r3v = *reinterpret_cast<const uint2*>(hs8 + (size_t)s3 * FD + f0);
    f32x2 e;
    e = __builtin_amdgcn_cvt_pk_f32_fp8((int)r0v.x, false); acc[0] += e.x*w0; acc[1] += e.y*w0;
    e = __builtin_amdgcn_cvt_pk_f32_fp8((int)r0v.x, true ); acc[2] += e.x*w0; acc[3] += e.y*w0;
    e = __builtin_amdgcn_cvt_pk_f32_fp8((int)r0v.y, false); acc[4] += e.x*w0; acc[5] += e.y*w0;
    e = __builtin_amdgcn_cvt_pk_f32_fp8((int)r0v.y, true ); acc[6] += e.x*w0; acc[7] += e.y*w0;
    e = __builtin_amdgcn_cvt_pk_f32_fp8((int)r1v.x, false); acc[0] += e.x*w1; acc[1] += e.y*w1;
    e = __builtin_amdgcn_cvt_pk_f32_fp8((int)r1v.x, true ); acc[2] += e.x*w1; acc[3] += e.y*w1;
    e = __builtin_amdgcn_cvt_pk_f32_fp8((int)r1v.y, false); acc[4] += e.x*w1; acc[5] += e.y*w1;
    e = __builtin_amdgcn_cvt_pk_f32_fp8((int)r1v.y, true ); acc[6] += e.x*w1; acc[7] += e.y*w1;
    e = __builtin_amdgcn_cvt_pk_f32_fp8((int)r2v.x, false); acc[0] += e.x*w2; acc[1] += e.y*w2;
    e = __builtin_amdgcn_cvt_pk_f32_fp8((int)r2v.x, true ); acc[2] += e.x*w2; acc[3] += e.y*w2;
    e = __builtin_amdgcn_cvt_pk_f32_fp8((int)r2v.y, false); acc[4] += e.x*w2; acc[5] += e.y*w2;
    e = __builtin_amdgcn_cvt_pk_f32_fp8((int)r2v.y, true ); acc[6] += e.x*w2; acc[7] += e.y*w2;
    e = __builtin_amdgcn_cvt_pk_f32_fp8((int)r3v.x, false); acc[0] += e.x*w3; acc[1] += e.y*w3;
    e = __builtin_amdgcn_cvt_pk_f32_fp8((int)r3v.x, true ); acc[2] += e.x*w3; acc[3] += e.y*w3;
    e = __builtin_amdgcn_cvt_pk_f32_fp8((int)r3v.y, false); acc[4] += e.x*w3; acc[5] += e.y*w3;
    e = __builtin_amdgcn_cvt_pk_f32_fp8((int)r3v.y, true ); acc[6] += e.x*w3; acc[7] += e.y*w3;
  }
  #pragma unroll
  for (int k = 0; k < 8; ++k){
    acc[k] += __shfl_xor(acc[k], 16);
    acc[k] += __shfl_xor(acc[k], 32);
  }
  float di = dinv[n];
  float ssq = 0.f;
  short8 o;
  #pragma unroll
  for (int k = 0; k < 8; ++k){
    float v = acc[k] * di + bias[f0 + k];
    v = v > 0.f ? v : 0.01f * v;
    ssq += v * v;
    o[k] = (short)f2b(v);
  }
  if (g == 0){
    *reinterpret_cast<short8*>(H + (size_t)n * KH + cOff + f0) = o;
    #pragma unroll
    for (int m = 1; m < 16; m <<= 1) ssq += __shfl_xor(ssq, m);
    if (ln == 0){
      if (cOff == 0) hh[n] = ssq;
      else           hh[n] += ssq;
    }
  }
}

__global__ void k_ss(const float* __restrict__ S, float* __restrict__ ss){
  int u = blockIdx.x, lane = threadIdx.x;
  const float* p = S + (size_t)u * KH + lane * 6;
  float s = 0.f;
  #pragma unroll
  for (int j = 0; j < 6; ++j){ float v = p[j]; s += v * v; }
  #pragma unroll
  for (int o = 32; o; o >>= 1) s += __shfl_down(s, o);
  if (lane == 0) ss[u] = s;
}

__global__ void k_out(const float* __restrict__ G, const float* __restrict__ lw,
                      const float* __restrict__ lb, float* __restrict__ out){
  int b = blockIdx.x, lane = threadIdx.x;
  float s = 0.f;
  #pragma unroll
  for (int j = 0; j < 4; ++j) s += G[b * NU + lane * 4 + j] * lw[lane * 4 + j];
  #pragma unroll
  for (int o = 32; o; o >>= 1) s += __shfl_down(s, o);
  if (lane == 0) out[b] = 1.f / (1.f + __expf(-(s + lb[0])));
}

extern "C" void kernel_launch(void* const* d_in, const int* in_sizes, int n_in,
                              void* d_out, int out_size, void* d_ws, size_t ws_size,
                              hipStream_t stream){
  const float* x   = (const float*)d_in[0];
  const int*   ei  = (const int*)d_in[1];
  const int*   bat = (const int*)d_in[2];
  const float* W1  = (const float*)d_in[3];
  const float* b1  = (const float*)d_in[4];
  const float* W2  = (const float*)d_in[5];
  const float* b2  = (const float*)d_in[6];
  const float* W3  = (const float*)d_in[7];
  const float* b3  = (const float*)d_in[8];
  const float* S   = (const float*)d_in[9];
  const float* lw  = (const float*)d_in[10];
  const float* lb  = (const float*)d_in[11];
  float* out = (float*)d_out;
  char* w = (char*)d_ws;

  int*      pos  = (int*)     (w + OFF_POS);
  float*    G    = (float*)   (w + OFF_G);
  int*      cnt  = (int*)     (w + OFF_CNT);
  unsigned* be   = (unsigned*)(w + OFF_BE);
  ushort*   col  = (ushort*)  (w + OFF_COL);
  float*    dinv = (float*)   (w + OFF_DINV);
  ushort*   xbf  = (ushort*)  (w + OFF_XBF);
  unsigned char* h8 = (unsigned char*)(w + OFF_H8);
  ushort*   H    = (ushort*)  (w + OFF_H);
  float*    hh   = (float*)   (w + OFF_HH);
  ushort*   Wt   = (ushort*)  (w + OFF_WT);
  ushort*   Sbf  = (ushort*)  (w + OFF_SBF);
  float*    ss   = (float*)   (w + OFF_SS);

  hipMemsetAsync(w, 0, 66048, stream);                      // pos + G

  k_convert<<<6250, 256, 0, stream>>>(x, xbf, 1600000);
  k_convert<<<96,   256, 0, stream>>>(S, Sbf, 24576);
  k_twc<<<128, 128, 0, stream>>>(W1, Wt);
  k_twc<<<128, 128, 0, stream>>>(W2, Wt + 16384);
  k_twc<<<128, 128, 0, stream>>>(W3, Wt + 32768);

  k_bin<<<196, 256, 0, stream>>>(ei, pos, be);
  k_build<<<NB, 256, 0, stream>>>(pos, be, cnt, col);
  k_dinv<<<196, 256, 0, stream>>>(cnt, dinv);

  dim3 blk(256);
  // layer 1: GEMM -> fp8 row-scaled table
  k_gemm<<<dim3(391, 1), blk, 0, stream>>>(xbf, FD, Wt, FD, h8, FD, NN, FD, dinv, 1);
  k_agg<<<12500, 256, 0, stream>>>(h8, dinv, cnt, col, b1, H, 0, hh);
  // layer 2
  k_gemm<<<dim3(391, 1), blk, 0, stream>>>(H, KH, Wt + 16384, FD, h8, FD, NN, FD, dinv, 1);
  k_agg<<<12500, 256, 0, stream>>>(h8, dinv, cnt, col, b2, H, 128, hh);
  // layer 3
  k_gemm<<<dim3(391, 1), blk, 0, stream>>>(H + 128, KH, Wt + 32768, FD, h8, FD, NN, FD, dinv, 1);
  k_agg<<<12500, 256, 0, stream>>>(h8, dinv, cnt, col, b3, H, 256, hh);

  k_ss<<<256, 64, 0, stream>>>(S, ss);
  // fused SOM: GEMM(H @ Sbf^T) + argmin + gaussian scatter into G
  k_gsom<<<391, 512, 0, stream>>>(H, Sbf, ss, hh, bat, G, NN);
  k_out<<<64, 64, 0, stream>>>(G, lw, lb, out);
}